// Round 11
// baseline (1760.029 us; speedup 1.0000x reference)
//
#include <hip/hip_runtime.h>
#include <hip/hip_fp16.h>
#include <math.h>

// ---- problem constants (match reference) ----
#define NNODES 100000
#define NEDGES 1600000
#define NLABEL 100000
#define DIM    64
#define ALPHA  0.25f            // 1/(NUM_LAYERS+1)
#define NB     782               // dst buckets of 128 nodes (dst >> 7)
#define NSLICE 4                 // src slices of 25000 nodes (3.2 MB fp16, L2-fit)
#define NBIN   (NB * NSLICE)     // 3128
#define NBLKF  256               // blocks for fill1 (1024 threads each)
#define BCAP   704               // per-bin tmp capacity (mean 511.5, sigma 22.6)
#define XS_LD  136               // padded LDS row stride (halfs) for MFMA tiles

typedef _Float16 half8 __attribute__((ext_vector_type(8)));
typedef float    f32x4 __attribute__((ext_vector_type(4)));

// ---- workspace layout (u32 words), total ~86.2 MB ----
constexpr size_t OFF_DIS   = 0;          // f32 [100096]
constexpr size_t OFF_GCUR  = 100096;     // int [3328]
constexpr size_t OFF_PARTL = 103424;     // f32 [2048] (loss partials)
constexpr size_t OFF_W1T   = 105472;     // half[8192] = 4096 words
constexpr size_t OFF_TMP   = 109568;     // int [NBIN*BCAP] = 2,202,112
constexpr size_t OFF_A     = 2311680;    // half buf (emb16 -> x2)   3,203,584 w
constexpr size_t OFF_B     = 5515264;    // half buf (x1 -> outf)    3,203,584 w
constexpr size_t OFF_OACC  = 8718848;    // half buf (alpha-accum)   3,203,584 w
constexpr size_t OFF_P     = 11922432;   // half [3][100096*64] = 9,610,752 w
constexpr size_t PSTRIDE   = 6407168;    // halfs per partial buffer

// convert fp32 embedding -> fp16; extra block: zero gcur + build W1T
__global__ void k_cvt(const float* __restrict__ emb, __half* __restrict__ emb16,
                      const float* __restrict__ W1, __half* __restrict__ w1t,
                      int* __restrict__ gcur) {
    int bid = blockIdx.x;
    int tid = threadIdx.x;
    if (bid < 6250) {
        int i = bid * 256 + tid;             // one float4 / thread, exactly 1.6M
        float4 v = ((const float4*)emb)[i];
        float2 bits;
        ((__half2*)&bits)[0] = __float22half2_rn(make_float2(v.x, v.y));
        ((__half2*)&bits)[1] = __float22half2_rn(make_float2(v.z, v.w));
        ((float2*)emb16)[i] = bits;
    } else {
        for (int i = tid; i < NBIN; i += 256) gcur[i] = 0;
        for (int idx = tid; idx < 8192; idx += 256) {
            int j = idx & 63;                // hidden col
            int k = idx >> 6;                // k index
            w1t[j * 128 + k] = __float2half_rn(W1[k * 64 + j]);
        }
    }
}

// single-pass binning by (dst-bucket, src-slice): per-block LDS hist ->
// one global reserve per bin -> packed 4B records (src<<7 | dst&127).
__global__ __launch_bounds__(1024) void k_fill1(
    const int* __restrict__ ei, int* __restrict__ gcur,
    int* __restrict__ tmp) {
    __shared__ int hist[NBIN];
    __shared__ int base[NBIN];
    int tid = threadIdx.x;
    const int chunk = (((NEDGES + NBLKF - 1) / NBLKF) + 3) & ~3;   // 6252 (x4)
    int e0 = blockIdx.x * chunk;
    int e1 = min(e0 + chunk, NEDGES);
    for (int i = tid; i < NBIN; i += 1024) hist[i] = 0;
    __syncthreads();
    const int* srcs = ei;
    const int* dsts = ei + NEDGES;
    for (int e = e0 + tid * 4; e + 3 < e1; e += 4096) {
        int4 s = *(const int4*)(srcs + e);
        int4 d = *(const int4*)(dsts + e);
        atomicAdd(&hist[(d.x >> 7) * NSLICE + s.x / 25000], 1);
        atomicAdd(&hist[(d.y >> 7) * NSLICE + s.y / 25000], 1);
        atomicAdd(&hist[(d.z >> 7) * NSLICE + s.z / 25000], 1);
        atomicAdd(&hist[(d.w >> 7) * NSLICE + s.w / 25000], 1);
    }
    __syncthreads();
    for (int b = tid; b < NBIN; b += 1024) {
        int c = hist[b];
        base[b] = c ? atomicAdd(&gcur[b], c) : 0;
        hist[b] = 0;
    }
    __syncthreads();
    for (int e = e0 + tid * 4; e + 3 < e1; e += 4096) {
        int4 s = *(const int4*)(srcs + e);
        int4 d = *(const int4*)(dsts + e);
        int b0 = (d.x >> 7) * NSLICE + s.x / 25000;
        int b1 = (d.y >> 7) * NSLICE + s.y / 25000;
        int b2 = (d.z >> 7) * NSLICE + s.z / 25000;
        int b3 = (d.w >> 7) * NSLICE + s.w / 25000;
        int l0 = atomicAdd(&hist[b0], 1);
        int l1 = atomicAdd(&hist[b1], 1);
        int l2 = atomicAdd(&hist[b2], 1);
        int l3 = atomicAdd(&hist[b3], 1);
        tmp[b0 * BCAP + min(base[b0] + l0, BCAP - 1)] = (s.x << 7) | (d.x & 127);
        tmp[b1 * BCAP + min(base[b1] + l1, BCAP - 1)] = (s.y << 7) | (d.y & 127);
        tmp[b2 * BCAP + min(base[b2] + l2, BCAP - 1)] = (s.z << 7) | (d.z & 127);
        tmp[b3 * BCAP + min(base[b3] + l3, BCAP - 1)] = (s.w << 7) | (d.w & 127);
    }
}

// per-bucket degree -> dis (reads the bucket's 4 bins)
__global__ __launch_bounds__(256) void k_deg(
    const int* __restrict__ gcur, const int* __restrict__ tmp,
    float* __restrict__ dis) {
    __shared__ int dcnt[128];
    int b = blockIdx.x;
    int tid = threadIdx.x;
    if (tid < 128) dcnt[tid] = 0;
    __syncthreads();
    for (int s = 0; s < NSLICE; ++s) {
        int bin = b * NSLICE + s;
        int n = min(gcur[bin], BCAP);
        const int* recs = tmp + (size_t)bin * BCAP;
        for (int i = tid; i < n; i += 256)
            atomicAdd(&dcnt[recs[i] & 127], 1);
    }
    __syncthreads();
    int node = (b << 7) + tid;
    if (tid < 128 && node < NNODES) {
        int d = dcnt[tid];
        dis[node] = d ? rsqrtf((float)d) : 0.0f;
    }
}

// partial propagate: block (bucket, slice); blockIdx%8 -> XCD, XCD-pair k owns
// slice k so gathers stay in an L2-resident 3.2MB slice. LDS fp32 accumulate,
// dense fp16 partial out (slice 0 -> x_next buffer, others -> P).
__global__ __launch_bounds__(256) void k_part(
    const int* __restrict__ gcur, const int* __restrict__ tmp,
    const float* __restrict__ dis, const __half* __restrict__ xin,
    __half* __restrict__ p0, __half* __restrict__ P) {
    __shared__ float acc[128 * 68];      // padded rows (bank spread)
    int bid = blockIdx.x;
    int g = bid >> 3, x = bid & 7;
    int slice = x >> 1;                  // XCD pair -> slice
    int bucket = g * 2 + (x & 1);        // [0, 782)
    int bin = bucket * NSLICE + slice;
    int n = min(gcur[bin], BCAP);
    const int* recs = tmp + (size_t)bin * BCAP;
    int tid = threadIdx.x;
    for (int i = tid; i < 128 * 68; i += 256) acc[i] = 0.f;
    __syncthreads();
    int grp = tid >> 4;                  // 16 edge-groups
    int c = tid & 15;                    // 4-dim chunk
    int i = grp;
    for (; i + 16 < n; i += 32) {        // 2 edges in flight per group
        int r0 = recs[i], r1 = recs[i + 16];
        int s0 = r0 >> 7, s1 = r1 >> 7;
        float w0 = dis[s0], w1 = dis[s1];
        float2 v0 = *(const float2*)(xin + (size_t)s0 * DIM + c * 4);
        float2 v1 = *(const float2*)(xin + (size_t)s1 * DIM + c * 4);
        float2 a0 = __half22float2(((__half2*)&v0)[0]);
        float2 a1 = __half22float2(((__half2*)&v0)[1]);
        float2 b0 = __half22float2(((__half2*)&v1)[0]);
        float2 b1 = __half22float2(((__half2*)&v1)[1]);
        float* p = &acc[(r0 & 127) * 68 + c * 4];
        atomicAdd(p + 0, w0 * a0.x);
        atomicAdd(p + 1, w0 * a0.y);
        atomicAdd(p + 2, w0 * a1.x);
        atomicAdd(p + 3, w0 * a1.y);
        float* q = &acc[(r1 & 127) * 68 + c * 4];
        atomicAdd(q + 0, w1 * b0.x);
        atomicAdd(q + 1, w1 * b0.y);
        atomicAdd(q + 2, w1 * b1.x);
        atomicAdd(q + 3, w1 * b1.y);
    }
    for (; i < n; i += 16) {
        int r = recs[i];
        int s = r >> 7;
        float w = dis[s];
        float2 v = *(const float2*)(xin + (size_t)s * DIM + c * 4);
        float2 a0 = __half22float2(((__half2*)&v)[0]);
        float2 a1 = __half22float2(((__half2*)&v)[1]);
        float* p = &acc[(r & 127) * 68 + c * 4];
        atomicAdd(p + 0, w * a0.x);
        atomicAdd(p + 1, w * a0.y);
        atomicAdd(p + 2, w * a1.x);
        atomicAdd(p + 3, w * a1.y);
    }
    __syncthreads();
    __half* dst = (slice == 0)
        ? p0 + ((size_t)bucket << 7) * DIM
        : P + (size_t)(slice - 1) * PSTRIDE + ((size_t)bucket << 7) * DIM;
    for (int k = tid; k < 2048; k += 256) {          // 2048 packs of 4 halfs
        int dl = k >> 4, d4 = (k & 15) * 4;
        float4 v = *(const float4*)&acc[dl * 68 + d4];
        float2 bits;
        ((__half2*)&bits)[0] = __float22half2_rn(make_float2(v.x, v.y));
        ((__half2*)&bits)[1] = __float22half2_rn(make_float2(v.z, v.w));
        ((float2*)dst)[k] = bits;
    }
}

// streaming reduce: y = dis * (p0 + p1 + p2 + p3); alpha-accumulation fused.
// MODE 0: x_next = y, oacc = ALPHA*(emb + y)
// MODE 1: x_next = y, oacc += ALPHA*y
// MODE 2: outf = oacc + ALPHA*y   (outf aliases y0 buffer; index-aligned RMW)
template <int MODE>
__global__ __launch_bounds__(256) void k_reduce(
    const float* __restrict__ dis, __half* __restrict__ y0,
    const __half* __restrict__ P, const __half* __restrict__ emb16,
    __half* __restrict__ oacc, __half* __restrict__ outf) {
    int i = blockIdx.x * 256 + threadIdx.x;     // one float4 = 8 halfs
    if (i >= (NNODES * DIM) / 8) return;
    float dn = dis[i >> 3];
    float4 ra = ((const float4*)y0)[i];
    float4 rb = ((const float4*)P)[i];
    float4 rc = ((const float4*)(P + PSTRIDE))[i];
    float4 rd = ((const float4*)(P + 2 * PSTRIDE))[i];
    float y[8];
#pragma unroll
    for (int h = 0; h < 4; ++h) {
        float2 fa = __half22float2(((__half2*)&ra)[h]);
        float2 fb = __half22float2(((__half2*)&rb)[h]);
        float2 fc = __half22float2(((__half2*)&rc)[h]);
        float2 fd = __half22float2(((__half2*)&rd)[h]);
        y[2 * h]     = dn * (((fa.x + fb.x) + (fc.x + fd.x)));
        y[2 * h + 1] = dn * (((fa.y + fb.y) + (fc.y + fd.y)));
    }
    if (MODE < 2) {
        float4 ybits;
#pragma unroll
        for (int h = 0; h < 4; ++h)
            ((__half2*)&ybits)[h] = __float22half2_rn(make_float2(y[2 * h], y[2 * h + 1]));
        ((float4*)y0)[i] = ybits;
    }
    if (MODE == 0) {
        float4 re = ((const float4*)emb16)[i];
        float4 obits;
#pragma unroll
        for (int h = 0; h < 4; ++h) {
            float2 fe = __half22float2(((__half2*)&re)[h]);
            ((__half2*)&obits)[h] = __float22half2_rn(make_float2(
                ALPHA * (fe.x + y[2 * h]), ALPHA * (fe.y + y[2 * h + 1])));
        }
        ((float4*)oacc)[i] = obits;
    } else if (MODE == 1) {
        float4 ro = ((const float4*)oacc)[i];
        float4 obits;
#pragma unroll
        for (int h = 0; h < 4; ++h) {
            float2 fo = __half22float2(((__half2*)&ro)[h]);
            ((__half2*)&obits)[h] = __float22half2_rn(make_float2(
                fo.x + ALPHA * y[2 * h], fo.y + ALPHA * y[2 * h + 1]));
        }
        ((float4*)oacc)[i] = obits;
    } else {
        float4 ro = ((const float4*)oacc)[i];
        float4 obits;
#pragma unroll
        for (int h = 0; h < 4; ++h) {
            float2 fo = __half22float2(((__half2*)&ro)[h]);
            ((__half2*)&obits)[h] = __float22half2_rn(make_float2(
                fo.x + ALPHA * y[2 * h], fo.y + ALPHA * y[2 * h + 1]));
        }
        ((float4*)outf)[i] = obits;
    }
}

// MFMA MLP: 64 labels/block, 4 waves = 4 M-tiles of 16 labels.
__global__ __launch_bounds__(256) void k_mlp(
    const __half* __restrict__ outf, const int* __restrict__ eli,
    const float* __restrict__ lbl, const __half* __restrict__ w1t,
    const float* __restrict__ b1, const float* __restrict__ W2,
    const float* __restrict__ b2, float* __restrict__ pred,
    float* __restrict__ partial) {
    __shared__ _Float16 xs[64 * XS_LD];
    __shared__ _Float16 ws1[64 * XS_LD];
    __shared__ float wsum[4];
    int tid = threadIdx.x;
    int lb = blockIdx.x * 64;

    for (int idx = tid; idx < 1024; idx += 256) {
        int row = idx >> 4, ch = idx & 15;
        *(float4*)&ws1[row * XS_LD + ch * 8] = ((const float4*)w1t)[idx];
    }
    {
        int lab = tid >> 2, q = tid & 3;
        int l = lb + lab;
        int li = (l < NLABEL) ? l : (NLABEL - 1);
        int s = eli[li];
        int t = eli[NLABEL + li];
        const __half* srow = outf + (size_t)s * DIM;
        const __half* trow = outf + (size_t)t * DIM;
#pragma unroll
        for (int i = 0; i < 4; ++i) {
            int cc = q + 4 * i;
            const __half* row = (cc < 8) ? srow + cc * 8 : trow + (cc - 8) * 8;
            *(float4*)&xs[lab * XS_LD + cc * 8] = *(const float4*)row;
        }
    }
    __syncthreads();

    int wid = tid >> 6;
    int lane = tid & 63;
    int lrow = lane & 15;
    int kgrp = lane >> 4;
    f32x4 acc[4];
#pragma unroll
    for (int nt = 0; nt < 4; ++nt) acc[nt] = (f32x4){0.f, 0.f, 0.f, 0.f};

#pragma unroll
    for (int ks = 0; ks < 4; ++ks) {
        half8 a = *(const half8*)&xs[(wid * 16 + lrow) * XS_LD + ks * 32 + kgrp * 8];
#pragma unroll
        for (int nt = 0; nt < 4; ++nt) {
            half8 b = *(const half8*)&ws1[(nt * 16 + lrow) * XS_LD + ks * 32 + kgrp * 8];
            acc[nt] = __builtin_amdgcn_mfma_f32_16x16x32_f16(a, b, acc[nt], 0, 0, 0);
        }
    }

    float p[4] = {0.f, 0.f, 0.f, 0.f};
#pragma unroll
    for (int nt = 0; nt < 4; ++nt) {
        float b1v = b1[nt * 16 + lrow];
        float w2v = W2[nt * 16 + lrow];
#pragma unroll
        for (int r = 0; r < 4; ++r)
            p[r] += fmaxf(acc[nt][r] + b1v, 0.f) * w2v;
    }
#pragma unroll
    for (int off = 1; off <= 8; off <<= 1) {
#pragma unroll
        for (int r = 0; r < 4; ++r) p[r] += __shfl_xor(p[r], off);
    }
    float lsum = 0.f;
    if (lrow == 0) {
        float b2v = b2[0];
#pragma unroll
        for (int r = 0; r < 4; ++r) {
            int l = lb + wid * 16 + kgrp * 4 + r;
            if (l < NLABEL) {
                float predv = p[r] + b2v;
                pred[l] = predv;
                float d = predv - lbl[l];
                lsum += d * d;
            }
        }
    }
    lsum += __shfl_xor(lsum, 16);
    lsum += __shfl_xor(lsum, 32);
    if (lane == 0) wsum[wid] = lsum;
    __syncthreads();
    if (tid == 0) partial[blockIdx.x] = (wsum[0] + wsum[1]) + (wsum[2] + wsum[3]);
}

__global__ void k_loss(const float* __restrict__ partial, float* __restrict__ lossout,
                       int n) {
    __shared__ float s[512];
    int tid = threadIdx.x;
    float v = 0.f;
    for (int i = tid; i < n; i += 512) v += partial[i];
    s[tid] = v;
    __syncthreads();
    for (int off = 256; off >= 1; off >>= 1) {
        if (tid < off) s[tid] += s[tid + off];
        __syncthreads();
    }
    if (tid == 0) lossout[0] = s[0] / (float)NLABEL;
}

extern "C" void kernel_launch(void* const* d_in, const int* in_sizes, int n_in,
                              void* d_out, int out_size, void* d_ws, size_t ws_size,
                              hipStream_t stream) {
    const int*   ei  = (const int*)d_in[0];
    const int*   eli = (const int*)d_in[1];
    const float* lbl = (const float*)d_in[2];
    const float* emb = (const float*)d_in[3];
    const float* W1  = (const float*)d_in[4];
    const float* b1  = (const float*)d_in[5];
    const float* W2  = (const float*)d_in[6];
    const float* b2  = (const float*)d_in[7];
    float* outp = (float*)d_out;               // pred[100000] ++ loss[1]

    char* wsb = (char*)d_ws;
    float*  dis   = (float*)wsb + OFF_DIS;
    int*    gcur  = (int*)wsb + OFF_GCUR;
    float*  part  = (float*)wsb + OFF_PARTL;
    __half* w1t   = (__half*)((int*)wsb + OFF_W1T);
    int*    tmp   = (int*)wsb + OFF_TMP;
    __half* bufA  = (__half*)((int*)wsb + OFF_A);     // emb16 -> x2
    __half* bufB  = (__half*)((int*)wsb + OFF_B);     // x1 -> outf
    __half* oacc  = (__half*)((int*)wsb + OFF_OACC);
    __half* P     = (__half*)((int*)wsb + OFF_P);

    const int T = 256;
    const int RGRID = (NNODES * DIM / 8 + T - 1) / T;   // 3125
    hipLaunchKernelGGL(k_cvt, dim3(6251), dim3(T), 0, stream, emb, bufA, W1, w1t, gcur);
    hipLaunchKernelGGL(k_fill1, dim3(NBLKF), dim3(1024), 0, stream, ei, gcur, tmp);
    hipLaunchKernelGGL(k_deg, dim3(NB), dim3(T), 0, stream, gcur, tmp, dis);

    // layer 1: x1(B) = P(emb16=A); oacc = ALPHA*(emb + x1)
    hipLaunchKernelGGL(k_part, dim3(NBIN), dim3(T), 0, stream, gcur, tmp, dis, bufA, bufB, P);
    hipLaunchKernelGGL((k_reduce<0>), dim3(RGRID), dim3(T), 0, stream, dis, bufB, P, bufA, oacc, (__half*)nullptr);
    // layer 2: x2(A) = P(x1=B); oacc += ALPHA*x2
    hipLaunchKernelGGL(k_part, dim3(NBIN), dim3(T), 0, stream, gcur, tmp, dis, bufB, bufA, P);
    hipLaunchKernelGGL((k_reduce<1>), dim3(RGRID), dim3(T), 0, stream, dis, bufA, P, (const __half*)nullptr, oacc, (__half*)nullptr);
    // layer 3: outf(B) = oacc + ALPHA * dis*(P(x2=A))
    hipLaunchKernelGGL(k_part, dim3(NBIN), dim3(T), 0, stream, gcur, tmp, dis, bufA, bufB, P);
    hipLaunchKernelGGL((k_reduce<2>), dim3(RGRID), dim3(T), 0, stream, dis, bufB, P, (const __half*)nullptr, oacc, bufB);

    const int MLPB = (NLABEL + 63) / 64;   // 1563
    hipLaunchKernelGGL(k_mlp, dim3(MLPB), dim3(T), 0, stream, bufB, eli, lbl, w1t, b1, W2, b2, outp, part);
    hipLaunchKernelGGL(k_loss, dim3(1), dim3(512), 0, stream, part, outp + NLABEL, MLPB);
}

// Round 12
// 274.673 us; speedup vs baseline: 6.4077x; 6.4077x over previous
//
#include <hip/hip_runtime.h>
#include <hip/hip_fp16.h>
#include <math.h>

// ---- problem constants (match reference) ----
#define NNODES 100000
#define NEDGES 1600000
#define NLABEL 100000
#define DIM    64
#define ALPHA  0.25f            // 1/(NUM_LAYERS+1)
#define NB     782               // dst buckets of 128 nodes (dst >> 7)
#define NSLICE 4                 // src slices of 25000 nodes (3.2 MB fp16, L2-fit)
#define NBIN   (NB * NSLICE)     // 3128
#define NBLKF  256               // blocks for fill1 (1024 threads each)
#define BCAP   704               // per-bin tmp capacity (mean 511.5, sigma 22.6)
#define XS_LD  136               // padded LDS row stride (halfs) for MFMA tiles

typedef _Float16 half8 __attribute__((ext_vector_type(8)));
typedef float    f32x4 __attribute__((ext_vector_type(4)));

// ---- workspace layout (u32 words), total ~86.2 MB ----
constexpr size_t OFF_DIS   = 0;          // f32 [100096]
constexpr size_t OFF_GCUR  = 100096;     // int [3328]
constexpr size_t OFF_PARTL = 103424;     // f32 [2048] (loss partials)
constexpr size_t OFF_W1T   = 105472;     // half[8192] = 4096 words
constexpr size_t OFF_TMP   = 109568;     // int [NBIN*BCAP] = 2,202,112
constexpr size_t OFF_A     = 2311680;    // half buf (emb16 -> x2)   3,203,584 w
constexpr size_t OFF_B     = 5515264;    // half buf (x1 -> outf)    3,203,584 w
constexpr size_t OFF_OACC  = 8718848;    // half buf (alpha-accum)   3,203,584 w
constexpr size_t OFF_P     = 11922432;   // half [3][100096*64] = 9,610,752 w
constexpr size_t PSTRIDE   = 6407168;    // halfs per partial buffer

// convert fp32 embedding -> fp16; extra block: zero gcur + build W1T
__global__ void k_cvt(const float* __restrict__ emb, __half* __restrict__ emb16,
                      const float* __restrict__ W1, __half* __restrict__ w1t,
                      int* __restrict__ gcur) {
    int bid = blockIdx.x;
    int tid = threadIdx.x;
    if (bid < 6250) {
        int i = bid * 256 + tid;             // one float4 / thread, exactly 1.6M
        float4 v = ((const float4*)emb)[i];
        float2 bits;
        ((__half2*)&bits)[0] = __float22half2_rn(make_float2(v.x, v.y));
        ((__half2*)&bits)[1] = __float22half2_rn(make_float2(v.z, v.w));
        ((float2*)emb16)[i] = bits;
    } else {
        for (int i = tid; i < NBIN; i += 256) gcur[i] = 0;
        for (int idx = tid; idx < 8192; idx += 256) {
            int j = idx & 63;                // hidden col
            int k = idx >> 6;                // k index
            w1t[j * 128 + k] = __float2half_rn(W1[k * 64 + j]);
        }
    }
}

// single-pass binning by (dst-bucket, src-slice): per-block LDS hist ->
// one global reserve per bin -> packed 4B records (src<<7 | dst&127).
__global__ __launch_bounds__(1024) void k_fill1(
    const int* __restrict__ ei, int* __restrict__ gcur,
    int* __restrict__ tmp) {
    __shared__ int hist[NBIN];
    __shared__ int base[NBIN];
    int tid = threadIdx.x;
    const int chunk = (((NEDGES + NBLKF - 1) / NBLKF) + 3) & ~3;   // 6252 (x4)
    int e0 = blockIdx.x * chunk;
    int e1 = min(e0 + chunk, NEDGES);
    for (int i = tid; i < NBIN; i += 1024) hist[i] = 0;
    __syncthreads();
    const int* srcs = ei;
    const int* dsts = ei + NEDGES;
    for (int e = e0 + tid * 4; e + 3 < e1; e += 4096) {
        int4 s = *(const int4*)(srcs + e);
        int4 d = *(const int4*)(dsts + e);
        atomicAdd(&hist[(d.x >> 7) * NSLICE + s.x / 25000], 1);
        atomicAdd(&hist[(d.y >> 7) * NSLICE + s.y / 25000], 1);
        atomicAdd(&hist[(d.z >> 7) * NSLICE + s.z / 25000], 1);
        atomicAdd(&hist[(d.w >> 7) * NSLICE + s.w / 25000], 1);
    }
    __syncthreads();
    for (int b = tid; b < NBIN; b += 1024) {
        int c = hist[b];
        base[b] = c ? atomicAdd(&gcur[b], c) : 0;
        hist[b] = 0;
    }
    __syncthreads();
    for (int e = e0 + tid * 4; e + 3 < e1; e += 4096) {
        int4 s = *(const int4*)(srcs + e);
        int4 d = *(const int4*)(dsts + e);
        int b0 = (d.x >> 7) * NSLICE + s.x / 25000;
        int b1 = (d.y >> 7) * NSLICE + s.y / 25000;
        int b2 = (d.z >> 7) * NSLICE + s.z / 25000;
        int b3 = (d.w >> 7) * NSLICE + s.w / 25000;
        int l0 = atomicAdd(&hist[b0], 1);
        int l1 = atomicAdd(&hist[b1], 1);
        int l2 = atomicAdd(&hist[b2], 1);
        int l3 = atomicAdd(&hist[b3], 1);
        tmp[b0 * BCAP + min(base[b0] + l0, BCAP - 1)] = (s.x << 7) | (d.x & 127);
        tmp[b1 * BCAP + min(base[b1] + l1, BCAP - 1)] = (s.y << 7) | (d.y & 127);
        tmp[b2 * BCAP + min(base[b2] + l2, BCAP - 1)] = (s.z << 7) | (d.z & 127);
        tmp[b3 * BCAP + min(base[b3] + l3, BCAP - 1)] = (s.w << 7) | (d.w & 127);
    }
}

// per-bucket degree -> dis (reads the bucket's 4 bins)
__global__ __launch_bounds__(256) void k_deg(
    const int* __restrict__ gcur, const int* __restrict__ tmp,
    float* __restrict__ dis) {
    __shared__ int dcnt[128];
    int b = blockIdx.x;
    int tid = threadIdx.x;
    if (tid < 128) dcnt[tid] = 0;
    __syncthreads();
    for (int s = 0; s < NSLICE; ++s) {
        int bin = b * NSLICE + s;
        int n = min(gcur[bin], BCAP);
        const int* recs = tmp + (size_t)bin * BCAP;
        for (int i = tid; i < n; i += 256)
            atomicAdd(&dcnt[recs[i] & 127], 1);
    }
    __syncthreads();
    int node = (b << 7) + tid;
    if (tid < 128 && node < NNODES) {
        int d = dcnt[tid];
        dis[node] = d ? rsqrtf((float)d) : 0.0f;
    }
}

// partial propagate v2: block (bucket, slice); blockIdx&7 -> XCD so XCD-pair k
// owns slice k and gathers stay in an L2-resident 3.2MB slice.
// NO accumulation atomics: reorder bin edges into per-dst CSR order in LDS
// (one cursor atomic per edge), then each wave owns 32 dst nodes and
// accumulates in registers with a 16-lane x 4-group gather + shuffle reduce.
__global__ __launch_bounds__(256) void k_part(
    const int* __restrict__ gcur, const int* __restrict__ tmp,
    const float* __restrict__ dis, const __half* __restrict__ xin,
    __half* __restrict__ p0, __half* __restrict__ P) {
    __shared__ int raw[BCAP];
    __shared__ int seg[BCAP];
    __shared__ int dcnt[128];
    __shared__ int sc[128];
    __shared__ int cur[128];
    int bid = blockIdx.x;
    int g = bid >> 3, x = bid & 7;
    int slice = x >> 1;                  // XCD pair -> slice
    int bucket = g * 2 + (x & 1);        // [0, 782)
    int bin = bucket * NSLICE + slice;
    int n = min(gcur[bin], BCAP);
    const int* recs = tmp + (size_t)bin * BCAP;
    int tid = threadIdx.x;
    if (tid < 128) dcnt[tid] = 0;
    __syncthreads();
    for (int i = tid; i < n; i += 256) {
        int t = recs[i];
        raw[i] = t;
        atomicAdd(&dcnt[t & 127], 1);
    }
    __syncthreads();
    if (tid < 128) sc[tid] = dcnt[tid];
    __syncthreads();
    for (int off = 1; off < 128; off <<= 1) {
        int t = 0;
        if (tid < 128) {
            t = sc[tid];
            if (tid >= off) t += sc[tid - off];
        }
        __syncthreads();
        if (tid < 128) sc[tid] = t;         // inclusive scan
        __syncthreads();
    }
    if (tid < 128) cur[tid] = sc[tid] - dcnt[tid];
    __syncthreads();
    for (int i = tid; i < n; i += 256) {
        int t = raw[i];
        int p = atomicAdd(&cur[t & 127], 1);
        seg[p] = t >> 7;                    // src, CSR-ordered by dst
    }
    __syncthreads();

    int wid = tid >> 6;                     // wave -> 32 dst nodes
    int lane = tid & 63;
    int grp = lane >> 4;                    // 4 edge groups
    int c = lane & 15;                      // 4-dim chunk
    __half* dst = (slice == 0)
        ? p0 + ((size_t)bucket << 7) * DIM
        : P + (size_t)(slice - 1) * PSTRIDE + ((size_t)bucket << 7) * DIM;
#pragma unroll 2
    for (int ln = wid * 32; ln < wid * 32 + 32; ++ln) {
        int en = sc[ln];
        int st = en - dcnt[ln];
        float4 a = {0.f, 0.f, 0.f, 0.f};
        for (int j = st + grp; j < en; j += 4) {
            int s = seg[j];
            float w = dis[s];
            float2 rv = *(const float2*)(xin + (size_t)s * DIM + c * 4);
            float2 f0 = __half22float2(((__half2*)&rv)[0]);
            float2 f1 = __half22float2(((__half2*)&rv)[1]);
            a.x += w * f0.x; a.y += w * f0.y;
            a.z += w * f1.x; a.w += w * f1.y;
        }
        a.x += __shfl_xor(a.x, 16); a.y += __shfl_xor(a.y, 16);
        a.z += __shfl_xor(a.z, 16); a.w += __shfl_xor(a.w, 16);
        a.x += __shfl_xor(a.x, 32); a.y += __shfl_xor(a.y, 32);
        a.z += __shfl_xor(a.z, 32); a.w += __shfl_xor(a.w, 32);
        if (lane < 16) {
            float2 bits;
            ((__half2*)&bits)[0] = __float22half2_rn(make_float2(a.x, a.y));
            ((__half2*)&bits)[1] = __float22half2_rn(make_float2(a.z, a.w));
            *(float2*)(dst + (size_t)ln * DIM + c * 4) = bits;
        }
    }
}

// streaming reduce: y = dis * (p0 + p1 + p2 + p3); alpha-accumulation fused.
// MODE 0: x_next = y, oacc = ALPHA*(emb + y)
// MODE 1: x_next = y, oacc += ALPHA*y
// MODE 2: outf = oacc + ALPHA*y   (outf aliases y0 buffer; index-aligned RMW)
template <int MODE>
__global__ __launch_bounds__(256) void k_reduce(
    const float* __restrict__ dis, __half* __restrict__ y0,
    const __half* __restrict__ P, const __half* __restrict__ emb16,
    __half* __restrict__ oacc, __half* __restrict__ outf) {
    int i = blockIdx.x * 256 + threadIdx.x;     // one float4 = 8 halfs
    if (i >= (NNODES * DIM) / 8) return;
    float dn = dis[i >> 3];
    float4 ra = ((const float4*)y0)[i];
    float4 rb = ((const float4*)P)[i];
    float4 rc = ((const float4*)(P + PSTRIDE))[i];
    float4 rd = ((const float4*)(P + 2 * PSTRIDE))[i];
    float y[8];
#pragma unroll
    for (int h = 0; h < 4; ++h) {
        float2 fa = __half22float2(((__half2*)&ra)[h]);
        float2 fb = __half22float2(((__half2*)&rb)[h]);
        float2 fc = __half22float2(((__half2*)&rc)[h]);
        float2 fd = __half22float2(((__half2*)&rd)[h]);
        y[2 * h]     = dn * (((fa.x + fb.x) + (fc.x + fd.x)));
        y[2 * h + 1] = dn * (((fa.y + fb.y) + (fc.y + fd.y)));
    }
    if (MODE < 2) {
        float4 ybits;
#pragma unroll
        for (int h = 0; h < 4; ++h)
            ((__half2*)&ybits)[h] = __float22half2_rn(make_float2(y[2 * h], y[2 * h + 1]));
        ((float4*)y0)[i] = ybits;
    }
    if (MODE == 0) {
        float4 re = ((const float4*)emb16)[i];
        float4 obits;
#pragma unroll
        for (int h = 0; h < 4; ++h) {
            float2 fe = __half22float2(((__half2*)&re)[h]);
            ((__half2*)&obits)[h] = __float22half2_rn(make_float2(
                ALPHA * (fe.x + y[2 * h]), ALPHA * (fe.y + y[2 * h + 1])));
        }
        ((float4*)oacc)[i] = obits;
    } else if (MODE == 1) {
        float4 ro = ((const float4*)oacc)[i];
        float4 obits;
#pragma unroll
        for (int h = 0; h < 4; ++h) {
            float2 fo = __half22float2(((__half2*)&ro)[h]);
            ((__half2*)&obits)[h] = __float22half2_rn(make_float2(
                fo.x + ALPHA * y[2 * h], fo.y + ALPHA * y[2 * h + 1]));
        }
        ((float4*)oacc)[i] = obits;
    } else {
        float4 ro = ((const float4*)oacc)[i];
        float4 obits;
#pragma unroll
        for (int h = 0; h < 4; ++h) {
            float2 fo = __half22float2(((__half2*)&ro)[h]);
            ((__half2*)&obits)[h] = __float22half2_rn(make_float2(
                fo.x + ALPHA * y[2 * h], fo.y + ALPHA * y[2 * h + 1]));
        }
        ((float4*)outf)[i] = obits;
    }
}

// MFMA MLP: 64 labels/block, 4 waves = 4 M-tiles of 16 labels.
__global__ __launch_bounds__(256) void k_mlp(
    const __half* __restrict__ outf, const int* __restrict__ eli,
    const float* __restrict__ lbl, const __half* __restrict__ w1t,
    const float* __restrict__ b1, const float* __restrict__ W2,
    const float* __restrict__ b2, float* __restrict__ pred,
    float* __restrict__ partial) {
    __shared__ _Float16 xs[64 * XS_LD];
    __shared__ _Float16 ws1[64 * XS_LD];
    __shared__ float wsum[4];
    int tid = threadIdx.x;
    int lb = blockIdx.x * 64;

    for (int idx = tid; idx < 1024; idx += 256) {
        int row = idx >> 4, ch = idx & 15;
        *(float4*)&ws1[row * XS_LD + ch * 8] = ((const float4*)w1t)[idx];
    }
    {
        int lab = tid >> 2, q = tid & 3;
        int l = lb + lab;
        int li = (l < NLABEL) ? l : (NLABEL - 1);
        int s = eli[li];
        int t = eli[NLABEL + li];
        const __half* srow = outf + (size_t)s * DIM;
        const __half* trow = outf + (size_t)t * DIM;
#pragma unroll
        for (int i = 0; i < 4; ++i) {
            int cc = q + 4 * i;
            const __half* row = (cc < 8) ? srow + cc * 8 : trow + (cc - 8) * 8;
            *(float4*)&xs[lab * XS_LD + cc * 8] = *(const float4*)row;
        }
    }
    __syncthreads();

    int wid = tid >> 6;
    int lane = tid & 63;
    int lrow = lane & 15;
    int kgrp = lane >> 4;
    f32x4 acc[4];
#pragma unroll
    for (int nt = 0; nt < 4; ++nt) acc[nt] = (f32x4){0.f, 0.f, 0.f, 0.f};

#pragma unroll
    for (int ks = 0; ks < 4; ++ks) {
        half8 a = *(const half8*)&xs[(wid * 16 + lrow) * XS_LD + ks * 32 + kgrp * 8];
#pragma unroll
        for (int nt = 0; nt < 4; ++nt) {
            half8 b = *(const half8*)&ws1[(nt * 16 + lrow) * XS_LD + ks * 32 + kgrp * 8];
            acc[nt] = __builtin_amdgcn_mfma_f32_16x16x32_f16(a, b, acc[nt], 0, 0, 0);
        }
    }

    float p[4] = {0.f, 0.f, 0.f, 0.f};
#pragma unroll
    for (int nt = 0; nt < 4; ++nt) {
        float b1v = b1[nt * 16 + lrow];
        float w2v = W2[nt * 16 + lrow];
#pragma unroll
        for (int r = 0; r < 4; ++r)
            p[r] += fmaxf(acc[nt][r] + b1v, 0.f) * w2v;
    }
#pragma unroll
    for (int off = 1; off <= 8; off <<= 1) {
#pragma unroll
        for (int r = 0; r < 4; ++r) p[r] += __shfl_xor(p[r], off);
    }
    float lsum = 0.f;
    if (lrow == 0) {
        float b2v = b2[0];
#pragma unroll
        for (int r = 0; r < 4; ++r) {
            int l = lb + wid * 16 + kgrp * 4 + r;
            if (l < NLABEL) {
                float predv = p[r] + b2v;
                pred[l] = predv;
                float d = predv - lbl[l];
                lsum += d * d;
            }
        }
    }
    lsum += __shfl_xor(lsum, 16);
    lsum += __shfl_xor(lsum, 32);
    if (lane == 0) wsum[wid] = lsum;
    __syncthreads();
    if (tid == 0) partial[blockIdx.x] = (wsum[0] + wsum[1]) + (wsum[2] + wsum[3]);
}

__global__ void k_loss(const float* __restrict__ partial, float* __restrict__ lossout,
                       int n) {
    __shared__ float s[512];
    int tid = threadIdx.x;
    float v = 0.f;
    for (int i = tid; i < n; i += 512) v += partial[i];
    s[tid] = v;
    __syncthreads();
    for (int off = 256; off >= 1; off >>= 1) {
        if (tid < off) s[tid] += s[tid + off];
        __syncthreads();
    }
    if (tid == 0) lossout[0] = s[0] / (float)NLABEL;
}

extern "C" void kernel_launch(void* const* d_in, const int* in_sizes, int n_in,
                              void* d_out, int out_size, void* d_ws, size_t ws_size,
                              hipStream_t stream) {
    const int*   ei  = (const int*)d_in[0];
    const int*   eli = (const int*)d_in[1];
    const float* lbl = (const float*)d_in[2];
    const float* emb = (const float*)d_in[3];
    const float* W1  = (const float*)d_in[4];
    const float* b1  = (const float*)d_in[5];
    const float* W2  = (const float*)d_in[6];
    const float* b2  = (const float*)d_in[7];
    float* outp = (float*)d_out;               // pred[100000] ++ loss[1]

    char* wsb = (char*)d_ws;
    float*  dis   = (float*)wsb + OFF_DIS;
    int*    gcur  = (int*)wsb + OFF_GCUR;
    float*  part  = (float*)wsb + OFF_PARTL;
    __half* w1t   = (__half*)((int*)wsb + OFF_W1T);
    int*    tmp   = (int*)wsb + OFF_TMP;
    __half* bufA  = (__half*)((int*)wsb + OFF_A);     // emb16 -> x2
    __half* bufB  = (__half*)((int*)wsb + OFF_B);     // x1 -> outf
    __half* oacc  = (__half*)((int*)wsb + OFF_OACC);
    __half* P     = (__half*)((int*)wsb + OFF_P);

    const int T = 256;
    const int RGRID = (NNODES * DIM / 8 + T - 1) / T;   // 3125
    hipLaunchKernelGGL(k_cvt, dim3(6251), dim3(T), 0, stream, emb, bufA, W1, w1t, gcur);
    hipLaunchKernelGGL(k_fill1, dim3(NBLKF), dim3(1024), 0, stream, ei, gcur, tmp);
    hipLaunchKernelGGL(k_deg, dim3(NB), dim3(T), 0, stream, gcur, tmp, dis);

    // layer 1: x1(B) = P(emb16=A); oacc = ALPHA*(emb + x1)
    hipLaunchKernelGGL(k_part, dim3(NBIN), dim3(T), 0, stream, gcur, tmp, dis, bufA, bufB, P);
    hipLaunchKernelGGL((k_reduce<0>), dim3(RGRID), dim3(T), 0, stream, dis, bufB, P, bufA, oacc, (__half*)nullptr);
    // layer 2: x2(A) = P(x1=B); oacc += ALPHA*x2
    hipLaunchKernelGGL(k_part, dim3(NBIN), dim3(T), 0, stream, gcur, tmp, dis, bufB, bufA, P);
    hipLaunchKernelGGL((k_reduce<1>), dim3(RGRID), dim3(T), 0, stream, dis, bufA, P, (const __half*)nullptr, oacc, (__half*)nullptr);
    // layer 3: outf(B) = oacc + ALPHA * dis*(P(x2=A))
    hipLaunchKernelGGL(k_part, dim3(NBIN), dim3(T), 0, stream, gcur, tmp, dis, bufA, bufB, P);
    hipLaunchKernelGGL((k_reduce<2>), dim3(RGRID), dim3(T), 0, stream, dis, bufB, P, (const __half*)nullptr, oacc, bufB);

    const int MLPB = (NLABEL + 63) / 64;   // 1563
    hipLaunchKernelGGL(k_mlp, dim3(MLPB), dim3(T), 0, stream, bufB, eli, lbl, w1t, b1, W2, b2, outp, part);
    hipLaunchKernelGGL(k_loss, dim3(1), dim3(512), 0, stream, part, outp + NLABEL, MLPB);
}

// Round 13
// 264.101 us; speedup vs baseline: 6.6642x; 1.0400x over previous
//
#include <hip/hip_runtime.h>
#include <hip/hip_fp16.h>
#include <math.h>

// ---- problem constants (match reference) ----
#define NNODES 100000
#define NEDGES 1600000
#define NLABEL 100000
#define DIM    64
#define ALPHA  0.25f            // 1/(NUM_LAYERS+1)
#define NB     782               // dst buckets of 128 nodes (dst >> 7)
#define NSLICE 4                 // src slices of 25000 nodes (3.2 MB fp16, L2-fit)
#define NBIN   (NB * NSLICE)     // 3128
#define NBLKF  256               // blocks for fill1 (1024 threads each)
#define BCAP   704               // per-bin tmp capacity (mean 511.5, sigma 22.6)
#define XS_LD  136               // padded LDS row stride (halfs) for MFMA tiles

typedef _Float16 half8 __attribute__((ext_vector_type(8)));
typedef float    f32x4 __attribute__((ext_vector_type(4)));

// ---- workspace layout (u32 words), total ~84.5 MB ----
constexpr size_t OFF_DIS   = 0;          // f32 [100096]
constexpr size_t OFF_GCUR  = 100096;     // int [3328]
constexpr size_t OFF_BBASE = 103424;     // int [3200] (NBIN+1)
constexpr size_t OFF_PARTL = 106624;     // f32 [2048] (loss partials)
constexpr size_t OFF_W1T   = 108672;     // half[8192] = 4096 words
constexpr size_t OFF_NOFF  = 112768;     // u16 [NBIN*128] = 200192 words
constexpr size_t OFF_CW    = 312960;     // int [1600000]
constexpr size_t OFF_A     = 1912960;    // half buf (emb16 -> x2)  3,203,584 w
constexpr size_t OFF_B     = 5116544;    // half buf (x1 -> outf)   3,203,584 w
constexpr size_t OFF_OACC  = 8320128;    // half buf (alpha-accum)  3,203,584 w
constexpr size_t OFF_P     = 11523712;   // half [3][PSTRIDE] = 9,610,752 w
constexpr size_t PSTRIDE   = 6407168;    // halfs per partial buffer
// tmp (int[NBIN*BCAP] = 2,202,112 w) aliases OFF_P: dead before first k_part.

// convert fp32 embedding -> fp16; extra block: zero gcur + build W1T
__global__ void k_cvt(const float* __restrict__ emb, __half* __restrict__ emb16,
                      const float* __restrict__ W1, __half* __restrict__ w1t,
                      int* __restrict__ gcur) {
    int bid = blockIdx.x;
    int tid = threadIdx.x;
    if (bid < 6250) {
        int i = bid * 256 + tid;             // one float4 / thread, exactly 1.6M
        float4 v = ((const float4*)emb)[i];
        float2 bits;
        ((__half2*)&bits)[0] = __float22half2_rn(make_float2(v.x, v.y));
        ((__half2*)&bits)[1] = __float22half2_rn(make_float2(v.z, v.w));
        ((float2*)emb16)[i] = bits;
    } else {
        for (int i = tid; i < NBIN; i += 256) gcur[i] = 0;
        for (int idx = tid; idx < 8192; idx += 256) {
            int j = idx & 63;                // hidden col
            int k = idx >> 6;                // k index
            w1t[j * 128 + k] = __float2half_rn(W1[k * 64 + j]);
        }
    }
}

// single-pass binning by (dst-bucket, src-slice): per-block LDS hist ->
// one global reserve per bin -> packed 4B records (src<<7 | dst&127).
__global__ __launch_bounds__(1024) void k_fill1(
    const int* __restrict__ ei, int* __restrict__ gcur,
    int* __restrict__ tmp) {
    __shared__ int hist[NBIN];
    __shared__ int base[NBIN];
    int tid = threadIdx.x;
    const int chunk = (((NEDGES + NBLKF - 1) / NBLKF) + 3) & ~3;   // 6252 (x4)
    int e0 = blockIdx.x * chunk;
    int e1 = min(e0 + chunk, NEDGES);
    for (int i = tid; i < NBIN; i += 1024) hist[i] = 0;
    __syncthreads();
    const int* srcs = ei;
    const int* dsts = ei + NEDGES;
    for (int e = e0 + tid * 4; e + 3 < e1; e += 4096) {
        int4 s = *(const int4*)(srcs + e);
        int4 d = *(const int4*)(dsts + e);
        atomicAdd(&hist[(d.x >> 7) * NSLICE + s.x / 25000], 1);
        atomicAdd(&hist[(d.y >> 7) * NSLICE + s.y / 25000], 1);
        atomicAdd(&hist[(d.z >> 7) * NSLICE + s.z / 25000], 1);
        atomicAdd(&hist[(d.w >> 7) * NSLICE + s.w / 25000], 1);
    }
    __syncthreads();
    for (int b = tid; b < NBIN; b += 1024) {
        int c = hist[b];
        base[b] = c ? atomicAdd(&gcur[b], c) : 0;
        hist[b] = 0;
    }
    __syncthreads();
    for (int e = e0 + tid * 4; e + 3 < e1; e += 4096) {
        int4 s = *(const int4*)(srcs + e);
        int4 d = *(const int4*)(dsts + e);
        int b0 = (d.x >> 7) * NSLICE + s.x / 25000;
        int b1 = (d.y >> 7) * NSLICE + s.y / 25000;
        int b2 = (d.z >> 7) * NSLICE + s.z / 25000;
        int b3 = (d.w >> 7) * NSLICE + s.w / 25000;
        int l0 = atomicAdd(&hist[b0], 1);
        int l1 = atomicAdd(&hist[b1], 1);
        int l2 = atomicAdd(&hist[b2], 1);
        int l3 = atomicAdd(&hist[b3], 1);
        tmp[b0 * BCAP + min(base[b0] + l0, BCAP - 1)] = (s.x << 7) | (d.x & 127);
        tmp[b1 * BCAP + min(base[b1] + l1, BCAP - 1)] = (s.y << 7) | (d.y & 127);
        tmp[b2 * BCAP + min(base[b2] + l2, BCAP - 1)] = (s.z << 7) | (d.z & 127);
        tmp[b3 * BCAP + min(base[b3] + l3, BCAP - 1)] = (s.w << 7) | (d.w & 127);
    }
}

// exclusive scan of capped bin counts -> bbase (4 bins/thread, 1024 threads)
__global__ __launch_bounds__(1024) void k_bscan(
    const int* __restrict__ gcur, int* __restrict__ bbase) {
    __shared__ int s[1024];
    int tid = threadIdx.x;
    int v[4];
    int sum = 0;
    for (int r = 0; r < 4; ++r) {
        int bin = tid * 4 + r;
        int c = (bin < NBIN) ? min(gcur[bin], BCAP) : 0;
        v[r] = sum;
        sum += c;
    }
    s[tid] = sum;
    __syncthreads();
    for (int off = 1; off < 1024; off <<= 1) {
        int t = s[tid];
        if (tid >= off) t += s[tid - off];
        __syncthreads();
        s[tid] = t;
        __syncthreads();
    }
    int pre = s[tid] - sum;
    for (int r = 0; r < 4; ++r) {
        int bin = tid * 4 + r;
        if (bin < NBIN) bbase[bin] = pre + v[r];
    }
    if (tid == 1023) bbase[NBIN] = s[1023];
}

// one-time CSR build: per bucket, read its 4 bins, per-(slice,node) degree,
// dis, per-bin u16 node offsets, reorder into persistent slice-ordered cw.
__global__ __launch_bounds__(256) void k_fill2(
    const int* __restrict__ gcur, const int* __restrict__ bbase,
    const int* __restrict__ tmp, float* __restrict__ dis,
    unsigned short* __restrict__ noff, int* __restrict__ cw) {
    __shared__ int raw[4 * BCAP];
    __shared__ int dcnt[4][128];
    __shared__ int cur[4][128];
    __shared__ int scw[256];
    int b = blockIdx.x, tid = threadIdx.x;
    if (tid < 128) {
        dcnt[0][tid] = 0; dcnt[1][tid] = 0; dcnt[2][tid] = 0; dcnt[3][tid] = 0;
    }
    __syncthreads();
    int ns[4];
    for (int s = 0; s < 4; ++s) {
        int bin = b * 4 + s;
        ns[s] = min(gcur[bin], BCAP);
        const int* recs = tmp + (size_t)bin * BCAP;
        for (int i = tid; i < ns[s]; i += 256) {
            int r = recs[i];
            raw[s * BCAP + i] = r;
            atomicAdd(&dcnt[s][r & 127], 1);
        }
    }
    __syncthreads();
    if (tid < 128) {
        int node = (b << 7) + tid;
        int deg = dcnt[0][tid] + dcnt[1][tid] + dcnt[2][tid] + dcnt[3][tid];
        if (node < NNODES) dis[node] = deg ? rsqrtf((float)deg) : 0.f;
    }
    for (int phase = 0; phase < 2; ++phase) {
        int s = phase * 2 + (tid >> 7);
        int ln = tid & 127;
        scw[tid] = dcnt[s][ln];
        __syncthreads();
        for (int off = 1; off < 128; off <<= 1) {
            int t = scw[tid];
            if (ln >= off) t += scw[tid - off];
            __syncthreads();
            scw[tid] = t;
            __syncthreads();
        }
        int excl = scw[tid] - dcnt[s][ln];
        cur[s][ln] = excl;
        noff[(size_t)(b * 4 + s) * 128 + ln] = (unsigned short)excl;
        __syncthreads();
    }
    for (int s = 0; s < 4; ++s) {
        int* outp = cw + bbase[b * 4 + s];
        for (int i = tid; i < ns[s]; i += 256) {
            int r = raw[s * BCAP + i];
            int p = atomicAdd(&cur[s][r & 127], 1);
            outp[p] = r >> 7;
        }
    }
}

// partial propagate v3: block (bucket, slice); blockIdx&7 -> XCD so XCD-pair k
// owns slice k (gathers stay in an L2-resident 3.2MB slice).
// Pure gather: wave = 4 nodes x 16 lanes, serial over each node's ~4 edges,
// 2-deep unrolled, no shuffles, no atomics, ~1KB LDS -> max occupancy.
__global__ __launch_bounds__(256) void k_part(
    const int* __restrict__ bbase, const unsigned short* __restrict__ noff,
    const int* __restrict__ cw, const float* __restrict__ dis,
    const __half* __restrict__ xin, __half* __restrict__ p0,
    __half* __restrict__ P) {
    __shared__ int no[129];
    int bid = blockIdx.x;
    int g = bid >> 3, x = bid & 7;
    int slice = x >> 1;                  // XCD pair -> slice
    int bucket = g * 2 + (x & 1);        // [0, 782)
    int bin = bucket * NSLICE + slice;
    int tid = threadIdx.x;
    int base = bbase[bin];
    if (tid < 128) no[tid] = noff[(size_t)bin * 128 + tid];
    if (tid == 128) no[128] = bbase[bin + 1] - base;
    __syncthreads();
    const int* seg = cw + base;
    int wid = tid >> 6, lane = tid & 63;
    int g4 = lane >> 4;                  // node within quad
    int c = lane & 15;                   // 4-dim chunk
    __half* dst = (slice == 0)
        ? p0 + ((size_t)bucket << 7) * DIM
        : P + (size_t)(slice - 1) * PSTRIDE + ((size_t)bucket << 7) * DIM;
#pragma unroll
    for (int k = 0; k < 8; ++k) {
        int node = wid * 32 + k * 4 + g4;
        int st = no[node], en = no[node + 1];
        float4 a = {0.f, 0.f, 0.f, 0.f}, a2 = {0.f, 0.f, 0.f, 0.f};
        int j = st;
        for (; j + 1 < en; j += 2) {
            int s0 = seg[j], s1 = seg[j + 1];
            float w0 = dis[s0], w1 = dis[s1];
            float2 r0 = *(const float2*)(xin + (size_t)s0 * DIM + c * 4);
            float2 r1 = *(const float2*)(xin + (size_t)s1 * DIM + c * 4);
            float2 f0 = __half22float2(((__half2*)&r0)[0]);
            float2 f1 = __half22float2(((__half2*)&r0)[1]);
            float2 h0 = __half22float2(((__half2*)&r1)[0]);
            float2 h1 = __half22float2(((__half2*)&r1)[1]);
            a.x += w0 * f0.x;  a.y += w0 * f0.y;
            a.z += w0 * f1.x;  a.w += w0 * f1.y;
            a2.x += w1 * h0.x; a2.y += w1 * h0.y;
            a2.z += w1 * h1.x; a2.w += w1 * h1.y;
        }
        if (j < en) {
            int s0 = seg[j];
            float w0 = dis[s0];
            float2 r0 = *(const float2*)(xin + (size_t)s0 * DIM + c * 4);
            float2 f0 = __half22float2(((__half2*)&r0)[0]);
            float2 f1 = __half22float2(((__half2*)&r0)[1]);
            a.x += w0 * f0.x; a.y += w0 * f0.y;
            a.z += w0 * f1.x; a.w += w0 * f1.y;
        }
        a.x += a2.x; a.y += a2.y; a.z += a2.z; a.w += a2.w;
        float2 bits;
        ((__half2*)&bits)[0] = __float22half2_rn(make_float2(a.x, a.y));
        ((__half2*)&bits)[1] = __float22half2_rn(make_float2(a.z, a.w));
        *(float2*)(dst + (size_t)node * DIM + c * 4) = bits;
    }
}

// streaming reduce: y = dis * (p0 + p1 + p2 + p3); alpha-accumulation fused.
// MODE 0: x_next = y, oacc = ALPHA*(emb + y)
// MODE 1: x_next = y, oacc += ALPHA*y
// MODE 2: outf = oacc + ALPHA*y   (outf aliases y0 buffer; index-aligned RMW)
template <int MODE>
__global__ __launch_bounds__(256) void k_reduce(
    const float* __restrict__ dis, __half* __restrict__ y0,
    const __half* __restrict__ P, const __half* __restrict__ emb16,
    __half* __restrict__ oacc, __half* __restrict__ outf) {
    int i = blockIdx.x * 256 + threadIdx.x;     // one float4 = 8 halfs
    if (i >= (NNODES * DIM) / 8) return;
    float dn = dis[i >> 3];
    float4 ra = ((const float4*)y0)[i];
    float4 rb = ((const float4*)P)[i];
    float4 rc = ((const float4*)(P + PSTRIDE))[i];
    float4 rd = ((const float4*)(P + 2 * PSTRIDE))[i];
    float y[8];
#pragma unroll
    for (int h = 0; h < 4; ++h) {
        float2 fa = __half22float2(((__half2*)&ra)[h]);
        float2 fb = __half22float2(((__half2*)&rb)[h]);
        float2 fc = __half22float2(((__half2*)&rc)[h]);
        float2 fd = __half22float2(((__half2*)&rd)[h]);
        y[2 * h]     = dn * (((fa.x + fb.x) + (fc.x + fd.x)));
        y[2 * h + 1] = dn * (((fa.y + fb.y) + (fc.y + fd.y)));
    }
    if (MODE < 2) {
        float4 ybits;
#pragma unroll
        for (int h = 0; h < 4; ++h)
            ((__half2*)&ybits)[h] = __float22half2_rn(make_float2(y[2 * h], y[2 * h + 1]));
        ((float4*)y0)[i] = ybits;
    }
    if (MODE == 0) {
        float4 re = ((const float4*)emb16)[i];
        float4 obits;
#pragma unroll
        for (int h = 0; h < 4; ++h) {
            float2 fe = __half22float2(((__half2*)&re)[h]);
            ((__half2*)&obits)[h] = __float22half2_rn(make_float2(
                ALPHA * (fe.x + y[2 * h]), ALPHA * (fe.y + y[2 * h + 1])));
        }
        ((float4*)oacc)[i] = obits;
    } else if (MODE == 1) {
        float4 ro = ((const float4*)oacc)[i];
        float4 obits;
#pragma unroll
        for (int h = 0; h < 4; ++h) {
            float2 fo = __half22float2(((__half2*)&ro)[h]);
            ((__half2*)&obits)[h] = __float22half2_rn(make_float2(
                fo.x + ALPHA * y[2 * h], fo.y + ALPHA * y[2 * h + 1]));
        }
        ((float4*)oacc)[i] = obits;
    } else {
        float4 ro = ((const float4*)oacc)[i];
        float4 obits;
#pragma unroll
        for (int h = 0; h < 4; ++h) {
            float2 fo = __half22float2(((__half2*)&ro)[h]);
            ((__half2*)&obits)[h] = __float22half2_rn(make_float2(
                fo.x + ALPHA * y[2 * h], fo.y + ALPHA * y[2 * h + 1]));
        }
        ((float4*)outf)[i] = obits;
    }
}

// MFMA MLP: 64 labels/block, 4 waves = 4 M-tiles of 16 labels.
__global__ __launch_bounds__(256) void k_mlp(
    const __half* __restrict__ outf, const int* __restrict__ eli,
    const float* __restrict__ lbl, const __half* __restrict__ w1t,
    const float* __restrict__ b1, const float* __restrict__ W2,
    const float* __restrict__ b2, float* __restrict__ pred,
    float* __restrict__ partial) {
    __shared__ _Float16 xs[64 * XS_LD];
    __shared__ _Float16 ws1[64 * XS_LD];
    __shared__ float wsum[4];
    int tid = threadIdx.x;
    int lb = blockIdx.x * 64;

    for (int idx = tid; idx < 1024; idx += 256) {
        int row = idx >> 4, ch = idx & 15;
        *(float4*)&ws1[row * XS_LD + ch * 8] = ((const float4*)w1t)[idx];
    }
    {
        int lab = tid >> 2, q = tid & 3;
        int l = lb + lab;
        int li = (l < NLABEL) ? l : (NLABEL - 1);
        int s = eli[li];
        int t = eli[NLABEL + li];
        const __half* srow = outf + (size_t)s * DIM;
        const __half* trow = outf + (size_t)t * DIM;
#pragma unroll
        for (int i = 0; i < 4; ++i) {
            int cc = q + 4 * i;
            const __half* row = (cc < 8) ? srow + cc * 8 : trow + (cc - 8) * 8;
            *(float4*)&xs[lab * XS_LD + cc * 8] = *(const float4*)row;
        }
    }
    __syncthreads();

    int wid = tid >> 6;
    int lane = tid & 63;
    int lrow = lane & 15;
    int kgrp = lane >> 4;
    f32x4 acc[4];
#pragma unroll
    for (int nt = 0; nt < 4; ++nt) acc[nt] = (f32x4){0.f, 0.f, 0.f, 0.f};

#pragma unroll
    for (int ks = 0; ks < 4; ++ks) {
        half8 a = *(const half8*)&xs[(wid * 16 + lrow) * XS_LD + ks * 32 + kgrp * 8];
#pragma unroll
        for (int nt = 0; nt < 4; ++nt) {
            half8 b = *(const half8*)&ws1[(nt * 16 + lrow) * XS_LD + ks * 32 + kgrp * 8];
            acc[nt] = __builtin_amdgcn_mfma_f32_16x16x32_f16(a, b, acc[nt], 0, 0, 0);
        }
    }

    float p[4] = {0.f, 0.f, 0.f, 0.f};
#pragma unroll
    for (int nt = 0; nt < 4; ++nt) {
        float b1v = b1[nt * 16 + lrow];
        float w2v = W2[nt * 16 + lrow];
#pragma unroll
        for (int r = 0; r < 4; ++r)
            p[r] += fmaxf(acc[nt][r] + b1v, 0.f) * w2v;
    }
#pragma unroll
    for (int off = 1; off <= 8; off <<= 1) {
#pragma unroll
        for (int r = 0; r < 4; ++r) p[r] += __shfl_xor(p[r], off);
    }
    float lsum = 0.f;
    if (lrow == 0) {
        float b2v = b2[0];
#pragma unroll
        for (int r = 0; r < 4; ++r) {
            int l = lb + wid * 16 + kgrp * 4 + r;
            if (l < NLABEL) {
                float predv = p[r] + b2v;
                pred[l] = predv;
                float d = predv - lbl[l];
                lsum += d * d;
            }
        }
    }
    lsum += __shfl_xor(lsum, 16);
    lsum += __shfl_xor(lsum, 32);
    if (lane == 0) wsum[wid] = lsum;
    __syncthreads();
    if (tid == 0) partial[blockIdx.x] = (wsum[0] + wsum[1]) + (wsum[2] + wsum[3]);
}

__global__ void k_loss(const float* __restrict__ partial, float* __restrict__ lossout,
                       int n) {
    __shared__ float s[512];
    int tid = threadIdx.x;
    float v = 0.f;
    for (int i = tid; i < n; i += 512) v += partial[i];
    s[tid] = v;
    __syncthreads();
    for (int off = 256; off >= 1; off >>= 1) {
        if (tid < off) s[tid] += s[tid + off];
        __syncthreads();
    }
    if (tid == 0) lossout[0] = s[0] / (float)NLABEL;
}

extern "C" void kernel_launch(void* const* d_in, const int* in_sizes, int n_in,
                              void* d_out, int out_size, void* d_ws, size_t ws_size,
                              hipStream_t stream) {
    const int*   ei  = (const int*)d_in[0];
    const int*   eli = (const int*)d_in[1];
    const float* lbl = (const float*)d_in[2];
    const float* emb = (const float*)d_in[3];
    const float* W1  = (const float*)d_in[4];
    const float* b1  = (const float*)d_in[5];
    const float* W2  = (const float*)d_in[6];
    const float* b2  = (const float*)d_in[7];
    float* outp = (float*)d_out;               // pred[100000] ++ loss[1]

    char* wsb = (char*)d_ws;
    float*  dis   = (float*)wsb + OFF_DIS;
    int*    gcur  = (int*)wsb + OFF_GCUR;
    int*    bbase = (int*)wsb + OFF_BBASE;
    float*  part  = (float*)wsb + OFF_PARTL;
    __half* w1t   = (__half*)((int*)wsb + OFF_W1T);
    unsigned short* noff = (unsigned short*)((int*)wsb + OFF_NOFF);
    int*    cw    = (int*)wsb + OFF_CW;
    __half* bufA  = (__half*)((int*)wsb + OFF_A);     // emb16 -> x2
    __half* bufB  = (__half*)((int*)wsb + OFF_B);     // x1 -> outf
    __half* oacc  = (__half*)((int*)wsb + OFF_OACC);
    __half* P     = (__half*)((int*)wsb + OFF_P);
    int*    tmp   = (int*)wsb + OFF_P;                // alias: dead before k_part

    const int T = 256;
    const int RGRID = (NNODES * DIM / 8 + T - 1) / T;   // 3125
    hipLaunchKernelGGL(k_cvt, dim3(6251), dim3(T), 0, stream, emb, bufA, W1, w1t, gcur);
    hipLaunchKernelGGL(k_fill1, dim3(NBLKF), dim3(1024), 0, stream, ei, gcur, tmp);
    hipLaunchKernelGGL(k_bscan, dim3(1), dim3(1024), 0, stream, gcur, bbase);
    hipLaunchKernelGGL(k_fill2, dim3(NB), dim3(T), 0, stream, gcur, bbase, tmp, dis, noff, cw);

    // layer 1: x1(B) = P(emb16=A); oacc = ALPHA*(emb + x1)
    hipLaunchKernelGGL(k_part, dim3(NBIN), dim3(T), 0, stream, bbase, noff, cw, dis, bufA, bufB, P);
    hipLaunchKernelGGL((k_reduce<0>), dim3(RGRID), dim3(T), 0, stream, dis, bufB, P, bufA, oacc, (__half*)nullptr);
    // layer 2: x2(A) = P(x1=B); oacc += ALPHA*x2
    hipLaunchKernelGGL(k_part, dim3(NBIN), dim3(T), 0, stream, bbase, noff, cw, dis, bufB, bufA, P);
    hipLaunchKernelGGL((k_reduce<1>), dim3(RGRID), dim3(T), 0, stream, dis, bufA, P, (const __half*)nullptr, oacc, (__half*)nullptr);
    // layer 3: outf(B) = oacc + ALPHA * dis*(P(x2=A))
    hipLaunchKernelGGL(k_part, dim3(NBIN), dim3(T), 0, stream, bbase, noff, cw, dis, bufA, bufB, P);
    hipLaunchKernelGGL((k_reduce<2>), dim3(RGRID), dim3(T), 0, stream, dis, bufB, P, (const __half*)nullptr, oacc, bufB);

    const int MLPB = (NLABEL + 63) / 64;   // 1563
    hipLaunchKernelGGL(k_mlp, dim3(MLPB), dim3(T), 0, stream, bufB, eli, lbl, w1t, b1, W2, b2, outp, part);
    hipLaunchKernelGGL(k_loss, dim3(1), dim3(512), 0, stream, part, outp + NLABEL, MLPB);
}

// Round 14
// 244.334 us; speedup vs baseline: 7.2034x; 1.0809x over previous
//
#include <hip/hip_runtime.h>
#include <hip/hip_fp16.h>
#include <math.h>

// ---- problem constants (match reference) ----
#define NNODES 100000
#define NEDGES 1600000
#define NLABEL 100000
#define DIM    64
#define ALPHA  0.25f            // 1/(NUM_LAYERS+1)
#define NB     782               // dst buckets of 128 nodes (dst >> 7)
#define NSLICE 4                 // src slices of 25000 nodes (3.2 MB fp16, L2-fit)
#define NBIN   (NB * NSLICE)     // 3128
#define NBLKF  256               // blocks for fill1 (1024 threads each)
#define BCAP   704               // per-bin tmp capacity (mean 511.5, sigma 22.6)
#define XS_LD  136               // padded LDS row stride (halfs) for MFMA tiles

typedef _Float16 half8 __attribute__((ext_vector_type(8)));
typedef float    f32x4 __attribute__((ext_vector_type(4)));

// ---- workspace layout (u32 words), total ~84.5 MB ----
constexpr size_t OFF_DIS   = 0;          // f32 [100096]
constexpr size_t OFF_GCUR  = 100096;     // int [3328]
constexpr size_t OFF_BBASE = 103424;     // int [3200] (NBIN+1)
constexpr size_t OFF_PARTL = 106624;     // f32 [2048] (loss partials)
constexpr size_t OFF_W1T   = 108672;     // half[8192] = 4096 words
constexpr size_t OFF_NOFF  = 112768;     // u16 [NBIN*128] = 200192 words
constexpr size_t OFF_CW    = 312960;     // int [1600000]
constexpr size_t OFF_A     = 1912960;    // half buf (emb16 -> x2)  3,203,584 w
constexpr size_t OFF_B     = 5116544;    // half buf (x1 -> outf)   3,203,584 w
constexpr size_t OFF_OACC  = 8320128;    // half buf (alpha-accum)  3,203,584 w
constexpr size_t OFF_P     = 11523712;   // half [3][PSTRIDE] = 9,610,752 w
constexpr size_t PSTRIDE   = 6407168;    // halfs per partial buffer
// tmp (int[NBIN*BCAP] = 2,202,112 w) aliases OFF_P: dead before first k_part.

// convert fp32 embedding -> fp16; extra block: zero gcur + build W1T
__global__ void k_cvt(const float* __restrict__ emb, __half* __restrict__ emb16,
                      const float* __restrict__ W1, __half* __restrict__ w1t,
                      int* __restrict__ gcur) {
    int bid = blockIdx.x;
    int tid = threadIdx.x;
    if (bid < 6250) {
        int i = bid * 256 + tid;             // one float4 / thread, exactly 1.6M
        float4 v = ((const float4*)emb)[i];
        float2 bits;
        ((__half2*)&bits)[0] = __float22half2_rn(make_float2(v.x, v.y));
        ((__half2*)&bits)[1] = __float22half2_rn(make_float2(v.z, v.w));
        ((float2*)emb16)[i] = bits;
    } else {
        for (int i = tid; i < NBIN; i += 256) gcur[i] = 0;
        for (int idx = tid; idx < 8192; idx += 256) {
            int j = idx & 63;                // hidden col
            int k = idx >> 6;                // k index
            w1t[j * 128 + k] = __float2half_rn(W1[k * 64 + j]);
        }
    }
}

// single-pass binning by (dst-bucket, src-slice)
__global__ __launch_bounds__(1024) void k_fill1(
    const int* __restrict__ ei, int* __restrict__ gcur,
    int* __restrict__ tmp) {
    __shared__ int hist[NBIN];
    __shared__ int base[NBIN];
    int tid = threadIdx.x;
    const int chunk = (((NEDGES + NBLKF - 1) / NBLKF) + 3) & ~3;   // 6252 (x4)
    int e0 = blockIdx.x * chunk;
    int e1 = min(e0 + chunk, NEDGES);
    for (int i = tid; i < NBIN; i += 1024) hist[i] = 0;
    __syncthreads();
    const int* srcs = ei;
    const int* dsts = ei + NEDGES;
    for (int e = e0 + tid * 4; e + 3 < e1; e += 4096) {
        int4 s = *(const int4*)(srcs + e);
        int4 d = *(const int4*)(dsts + e);
        atomicAdd(&hist[(d.x >> 7) * NSLICE + s.x / 25000], 1);
        atomicAdd(&hist[(d.y >> 7) * NSLICE + s.y / 25000], 1);
        atomicAdd(&hist[(d.z >> 7) * NSLICE + s.z / 25000], 1);
        atomicAdd(&hist[(d.w >> 7) * NSLICE + s.w / 25000], 1);
    }
    __syncthreads();
    for (int b = tid; b < NBIN; b += 1024) {
        int c = hist[b];
        base[b] = c ? atomicAdd(&gcur[b], c) : 0;
        hist[b] = 0;
    }
    __syncthreads();
    for (int e = e0 + tid * 4; e + 3 < e1; e += 4096) {
        int4 s = *(const int4*)(srcs + e);
        int4 d = *(const int4*)(dsts + e);
        int b0 = (d.x >> 7) * NSLICE + s.x / 25000;
        int b1 = (d.y >> 7) * NSLICE + s.y / 25000;
        int b2 = (d.z >> 7) * NSLICE + s.z / 25000;
        int b3 = (d.w >> 7) * NSLICE + s.w / 25000;
        int l0 = atomicAdd(&hist[b0], 1);
        int l1 = atomicAdd(&hist[b1], 1);
        int l2 = atomicAdd(&hist[b2], 1);
        int l3 = atomicAdd(&hist[b3], 1);
        tmp[b0 * BCAP + min(base[b0] + l0, BCAP - 1)] = (s.x << 7) | (d.x & 127);
        tmp[b1 * BCAP + min(base[b1] + l1, BCAP - 1)] = (s.y << 7) | (d.y & 127);
        tmp[b2 * BCAP + min(base[b2] + l2, BCAP - 1)] = (s.z << 7) | (d.z & 127);
        tmp[b3 * BCAP + min(base[b3] + l3, BCAP - 1)] = (s.w << 7) | (d.w & 127);
    }
}

// exclusive scan of capped bin counts -> bbase (4 bins/thread, 1024 threads)
__global__ __launch_bounds__(1024) void k_bscan(
    const int* __restrict__ gcur, int* __restrict__ bbase) {
    __shared__ int s[1024];
    int tid = threadIdx.x;
    int v[4];
    int sum = 0;
    for (int r = 0; r < 4; ++r) {
        int bin = tid * 4 + r;
        int c = (bin < NBIN) ? min(gcur[bin], BCAP) : 0;
        v[r] = sum;
        sum += c;
    }
    s[tid] = sum;
    __syncthreads();
    for (int off = 1; off < 1024; off <<= 1) {
        int t = s[tid];
        if (tid >= off) t += s[tid - off];
        __syncthreads();
        s[tid] = t;
        __syncthreads();
    }
    int pre = s[tid] - sum;
    for (int r = 0; r < 4; ++r) {
        int bin = tid * 4 + r;
        if (bin < NBIN) bbase[bin] = pre + v[r];
    }
    if (tid == 1023) bbase[NBIN] = s[1023];
}

// one-time CSR build: per bucket, read its 4 bins, per-(slice,node) degree,
// dis, per-bin u16 node offsets, reorder into persistent slice-ordered cw.
__global__ __launch_bounds__(256) void k_fill2(
    const int* __restrict__ gcur, const int* __restrict__ bbase,
    const int* __restrict__ tmp, float* __restrict__ dis,
    unsigned short* __restrict__ noff, int* __restrict__ cw) {
    __shared__ int raw[4 * BCAP];
    __shared__ int dcnt[4][128];
    __shared__ int cur[4][128];
    __shared__ int scw[256];
    int b = blockIdx.x, tid = threadIdx.x;
    if (tid < 128) {
        dcnt[0][tid] = 0; dcnt[1][tid] = 0; dcnt[2][tid] = 0; dcnt[3][tid] = 0;
    }
    __syncthreads();
    int ns[4];
    for (int s = 0; s < 4; ++s) {
        int bin = b * 4 + s;
        ns[s] = min(gcur[bin], BCAP);
        const int* recs = tmp + (size_t)bin * BCAP;
        for (int i = tid; i < ns[s]; i += 256) {
            int r = recs[i];
            raw[s * BCAP + i] = r;
            atomicAdd(&dcnt[s][r & 127], 1);
        }
    }
    __syncthreads();
    if (tid < 128) {
        int node = (b << 7) + tid;
        int deg = dcnt[0][tid] + dcnt[1][tid] + dcnt[2][tid] + dcnt[3][tid];
        if (node < NNODES) dis[node] = deg ? rsqrtf((float)deg) : 0.f;
    }
    for (int phase = 0; phase < 2; ++phase) {
        int s = phase * 2 + (tid >> 7);
        int ln = tid & 127;
        scw[tid] = dcnt[s][ln];
        __syncthreads();
        for (int off = 1; off < 128; off <<= 1) {
            int t = scw[tid];
            if (ln >= off) t += scw[tid - off];
            __syncthreads();
            scw[tid] = t;
            __syncthreads();
        }
        int excl = scw[tid] - dcnt[s][ln];
        cur[s][ln] = excl;
        noff[(size_t)(b * 4 + s) * 128 + ln] = (unsigned short)excl;
        __syncthreads();
    }
    for (int s = 0; s < 4; ++s) {
        int* outp = cw + bbase[b * 4 + s];
        for (int i = tid; i < ns[s]; i += 256) {
            int r = raw[s * BCAP + i];
            int p = atomicAdd(&cur[s][r & 127], 1);
            outp[p] = r >> 7;
        }
    }
}

// partial propagate v4: block = (bucket, slice, half of 64 nodes); bid&7 keeps
// slice -> XCD-pair affinity (gathers stay in an L2-resident 3.2MB slice).
// Packed fp16 accumulation (v_pk_add_f16 / v_pk_fma_f16), 4-deep edge ILP,
// no shuffles / atomics / cvts. SCALED=1: input rows pre-multiplied by dis[src]
// (layers 2-3); SCALED=0: weight applied inline (layer 1).
template <int SCALED>
__global__ __launch_bounds__(256) void k_part(
    const int* __restrict__ bbase, const unsigned short* __restrict__ noff,
    const int* __restrict__ cw, const float* __restrict__ dis,
    const __half* __restrict__ xin, __half* __restrict__ p0,
    __half* __restrict__ P) {
    __shared__ int no[65];
    int bid = blockIdx.x;
    int x = bid & 7;
    int slice = x >> 1;                      // XCD pair -> slice
    int half = (bid >> 3) & 1;               // which 64 nodes of the bucket
    int bucket = (bid >> 4) * 2 + (x & 1);   // [0, 782)
    int bin = bucket * NSLICE + slice;
    int tid = threadIdx.x;
    int base = bbase[bin];
    int nb0 = half << 6;
    if (tid < 64) no[tid] = noff[(size_t)bin * 128 + nb0 + tid];
    if (tid == 64)
        no[64] = half ? (bbase[bin + 1] - base) : noff[(size_t)bin * 128 + 64];
    __syncthreads();
    const int* seg = cw + base;
    int grp = tid >> 4;                      // 16 groups
    int c = tid & 15;                        // 4-dim chunk
    __half* dstbase = (slice == 0) ? p0 : P + (size_t)(slice - 1) * PSTRIDE;
    const __half2 zero = __float2half2_rn(0.f);
#pragma unroll
    for (int k = 0; k < 4; ++k) {
        int ln = grp * 4 + k;
        int st = no[ln], en = no[ln + 1];
        __half2 alo = zero, ahi = zero, blo = zero, bhi = zero;
        int j = st;
        for (; j + 3 < en; j += 4) {
            int s0 = seg[j], s1 = seg[j + 1], s2 = seg[j + 2], s3 = seg[j + 3];
            float2 r0 = *(const float2*)(xin + (size_t)s0 * DIM + c * 4);
            float2 r1 = *(const float2*)(xin + (size_t)s1 * DIM + c * 4);
            float2 r2 = *(const float2*)(xin + (size_t)s2 * DIM + c * 4);
            float2 r3 = *(const float2*)(xin + (size_t)s3 * DIM + c * 4);
            if (SCALED) {
                alo = __hadd2(alo, ((__half2*)&r0)[0]);
                ahi = __hadd2(ahi, ((__half2*)&r0)[1]);
                blo = __hadd2(blo, ((__half2*)&r1)[0]);
                bhi = __hadd2(bhi, ((__half2*)&r1)[1]);
                alo = __hadd2(alo, ((__half2*)&r2)[0]);
                ahi = __hadd2(ahi, ((__half2*)&r2)[1]);
                blo = __hadd2(blo, ((__half2*)&r3)[0]);
                bhi = __hadd2(bhi, ((__half2*)&r3)[1]);
            } else {
                __half2 w0 = __float2half2_rn(dis[s0]);
                __half2 w1 = __float2half2_rn(dis[s1]);
                __half2 w2 = __float2half2_rn(dis[s2]);
                __half2 w3 = __float2half2_rn(dis[s3]);
                alo = __hfma2(w0, ((__half2*)&r0)[0], alo);
                ahi = __hfma2(w0, ((__half2*)&r0)[1], ahi);
                blo = __hfma2(w1, ((__half2*)&r1)[0], blo);
                bhi = __hfma2(w1, ((__half2*)&r1)[1], bhi);
                alo = __hfma2(w2, ((__half2*)&r2)[0], alo);
                ahi = __hfma2(w2, ((__half2*)&r2)[1], ahi);
                blo = __hfma2(w3, ((__half2*)&r3)[0], blo);
                bhi = __hfma2(w3, ((__half2*)&r3)[1], bhi);
            }
        }
        if (j + 1 < en) {
            int s0 = seg[j], s1 = seg[j + 1];
            float2 r0 = *(const float2*)(xin + (size_t)s0 * DIM + c * 4);
            float2 r1 = *(const float2*)(xin + (size_t)s1 * DIM + c * 4);
            if (SCALED) {
                alo = __hadd2(alo, ((__half2*)&r0)[0]);
                ahi = __hadd2(ahi, ((__half2*)&r0)[1]);
                blo = __hadd2(blo, ((__half2*)&r1)[0]);
                bhi = __hadd2(bhi, ((__half2*)&r1)[1]);
            } else {
                __half2 w0 = __float2half2_rn(dis[s0]);
                __half2 w1 = __float2half2_rn(dis[s1]);
                alo = __hfma2(w0, ((__half2*)&r0)[0], alo);
                ahi = __hfma2(w0, ((__half2*)&r0)[1], ahi);
                blo = __hfma2(w1, ((__half2*)&r1)[0], blo);
                bhi = __hfma2(w1, ((__half2*)&r1)[1], bhi);
            }
            j += 2;
        }
        if (j < en) {
            int s0 = seg[j];
            float2 r0 = *(const float2*)(xin + (size_t)s0 * DIM + c * 4);
            if (SCALED) {
                alo = __hadd2(alo, ((__half2*)&r0)[0]);
                ahi = __hadd2(ahi, ((__half2*)&r0)[1]);
            } else {
                __half2 w0 = __float2half2_rn(dis[s0]);
                alo = __hfma2(w0, ((__half2*)&r0)[0], alo);
                ahi = __hfma2(w0, ((__half2*)&r0)[1], ahi);
            }
        }
        float2 bits;
        ((__half2*)&bits)[0] = __hadd2(alo, blo);
        ((__half2*)&bits)[1] = __hadd2(ahi, bhi);
        size_t row = (size_t)((bucket << 7) + nb0 + ln);
        *(float2*)(dstbase + row * DIM + c * 4) = bits;
    }
}

// streaming reduce: S = p0+p1+p2+p3 (fp32); alpha-accumulation fused.
// Stored next-layer input is PRE-SCALED: x' = dis^2 * S  (= dis * x_next).
// MODE 0: y0 = dis^2*S, oacc = ALPHA*(emb + dis*S)
// MODE 1: y0 = dis^2*S, oacc += ALPHA*dis*S
// MODE 2: outf = oacc + ALPHA*dis*S
template <int MODE>
__global__ __launch_bounds__(256) void k_reduce(
    const float* __restrict__ dis, __half* __restrict__ y0,
    const __half* __restrict__ P, const __half* __restrict__ emb16,
    __half* __restrict__ oacc, __half* __restrict__ outf) {
    int i = blockIdx.x * 256 + threadIdx.x;     // one float4 = 8 halfs
    if (i >= (NNODES * DIM) / 8) return;
    float dn = dis[i >> 3];
    float4 ra = ((const float4*)y0)[i];
    float4 rb = ((const float4*)P)[i];
    float4 rc = ((const float4*)(P + PSTRIDE))[i];
    float4 rd = ((const float4*)(P + 2 * PSTRIDE))[i];
    float yv[8];                                 // dis * S (true x_next)
#pragma unroll
    for (int h = 0; h < 4; ++h) {
        float2 fa = __half22float2(((__half2*)&ra)[h]);
        float2 fb = __half22float2(((__half2*)&rb)[h]);
        float2 fc = __half22float2(((__half2*)&rc)[h]);
        float2 fd = __half22float2(((__half2*)&rd)[h]);
        yv[2 * h]     = dn * ((fa.x + fb.x) + (fc.x + fd.x));
        yv[2 * h + 1] = dn * ((fa.y + fb.y) + (fc.y + fd.y));
    }
    if (MODE < 2) {                              // store pre-scaled x' = dn*y
        float4 ybits;
#pragma unroll
        for (int h = 0; h < 4; ++h)
            ((__half2*)&ybits)[h] = __float22half2_rn(
                make_float2(dn * yv[2 * h], dn * yv[2 * h + 1]));
        ((float4*)y0)[i] = ybits;
    }
    if (MODE == 0) {
        float4 re = ((const float4*)emb16)[i];
        float4 obits;
#pragma unroll
        for (int h = 0; h < 4; ++h) {
            float2 fe = __half22float2(((__half2*)&re)[h]);
            ((__half2*)&obits)[h] = __float22half2_rn(make_float2(
                ALPHA * (fe.x + yv[2 * h]), ALPHA * (fe.y + yv[2 * h + 1])));
        }
        ((float4*)oacc)[i] = obits;
    } else if (MODE == 1) {
        float4 ro = ((const float4*)oacc)[i];
        float4 obits;
#pragma unroll
        for (int h = 0; h < 4; ++h) {
            float2 fo = __half22float2(((__half2*)&ro)[h]);
            ((__half2*)&obits)[h] = __float22half2_rn(make_float2(
                fo.x + ALPHA * yv[2 * h], fo.y + ALPHA * yv[2 * h + 1]));
        }
        ((float4*)oacc)[i] = obits;
    } else {
        float4 ro = ((const float4*)oacc)[i];
        float4 obits;
#pragma unroll
        for (int h = 0; h < 4; ++h) {
            float2 fo = __half22float2(((__half2*)&ro)[h]);
            ((__half2*)&obits)[h] = __float22half2_rn(make_float2(
                fo.x + ALPHA * yv[2 * h], fo.y + ALPHA * yv[2 * h + 1]));
        }
        ((float4*)outf)[i] = obits;
    }
}

// MFMA MLP: 64 labels/block, 4 waves = 4 M-tiles of 16 labels.
__global__ __launch_bounds__(256) void k_mlp(
    const __half* __restrict__ outf, const int* __restrict__ eli,
    const float* __restrict__ lbl, const __half* __restrict__ w1t,
    const float* __restrict__ b1, const float* __restrict__ W2,
    const float* __restrict__ b2, float* __restrict__ pred,
    float* __restrict__ partial) {
    __shared__ _Float16 xs[64 * XS_LD];
    __shared__ _Float16 ws1[64 * XS_LD];
    __shared__ float wsum[4];
    int tid = threadIdx.x;
    int lb = blockIdx.x * 64;

    for (int idx = tid; idx < 1024; idx += 256) {
        int row = idx >> 4, ch = idx & 15;
        *(float4*)&ws1[row * XS_LD + ch * 8] = ((const float4*)w1t)[idx];
    }
    {
        int lab = tid >> 2, q = tid & 3;
        int l = lb + lab;
        int li = (l < NLABEL) ? l : (NLABEL - 1);
        int s = eli[li];
        int t = eli[NLABEL + li];
        const __half* srow = outf + (size_t)s * DIM;
        const __half* trow = outf + (size_t)t * DIM;
#pragma unroll
        for (int i = 0; i < 4; ++i) {
            int cc = q + 4 * i;
            const __half* row = (cc < 8) ? srow + cc * 8 : trow + (cc - 8) * 8;
            *(float4*)&xs[lab * XS_LD + cc * 8] = *(const float4*)row;
        }
    }
    __syncthreads();

    int wid = tid >> 6;
    int lane = tid & 63;
    int lrow = lane & 15;
    int kgrp = lane >> 4;
    f32x4 acc[4];
#pragma unroll
    for (int nt = 0; nt < 4; ++nt) acc[nt] = (f32x4){0.f, 0.f, 0.f, 0.f};

#pragma unroll
    for (int ks = 0; ks < 4; ++ks) {
        half8 a = *(const half8*)&xs[(wid * 16 + lrow) * XS_LD + ks * 32 + kgrp * 8];
#pragma unroll
        for (int nt = 0; nt < 4; ++nt) {
            half8 b = *(const half8*)&ws1[(nt * 16 + lrow) * XS_LD + ks * 32 + kgrp * 8];
            acc[nt] = __builtin_amdgcn_mfma_f32_16x16x32_f16(a, b, acc[nt], 0, 0, 0);
        }
    }

    float p[4] = {0.f, 0.f, 0.f, 0.f};
#pragma unroll
    for (int nt = 0; nt < 4; ++nt) {
        float b1v = b1[nt * 16 + lrow];
        float w2v = W2[nt * 16 + lrow];
#pragma unroll
        for (int r = 0; r < 4; ++r)
            p[r] += fmaxf(acc[nt][r] + b1v, 0.f) * w2v;
    }
#pragma unroll
    for (int off = 1; off <= 8; off <<= 1) {
#pragma unroll
        for (int r = 0; r < 4; ++r) p[r] += __shfl_xor(p[r], off);
    }
    float lsum = 0.f;
    if (lrow == 0) {
        float b2v = b2[0];
#pragma unroll
        for (int r = 0; r < 4; ++r) {
            int l = lb + wid * 16 + kgrp * 4 + r;
            if (l < NLABEL) {
                float predv = p[r] + b2v;
                pred[l] = predv;
                float d = predv - lbl[l];
                lsum += d * d;
            }
        }
    }
    lsum += __shfl_xor(lsum, 16);
    lsum += __shfl_xor(lsum, 32);
    if (lane == 0) wsum[wid] = lsum;
    __syncthreads();
    if (tid == 0) partial[blockIdx.x] = (wsum[0] + wsum[1]) + (wsum[2] + wsum[3]);
}

__global__ void k_loss(const float* __restrict__ partial, float* __restrict__ lossout,
                       int n) {
    __shared__ float s[512];
    int tid = threadIdx.x;
    float v = 0.f;
    for (int i = tid; i < n; i += 512) v += partial[i];
    s[tid] = v;
    __syncthreads();
    for (int off = 256; off >= 1; off >>= 1) {
        if (tid < off) s[tid] += s[tid + off];
        __syncthreads();
    }
    if (tid == 0) lossout[0] = s[0] / (float)NLABEL;
}

extern "C" void kernel_launch(void* const* d_in, const int* in_sizes, int n_in,
                              void* d_out, int out_size, void* d_ws, size_t ws_size,
                              hipStream_t stream) {
    const int*   ei  = (const int*)d_in[0];
    const int*   eli = (const int*)d_in[1];
    const float* lbl = (const float*)d_in[2];
    const float* emb = (const float*)d_in[3];
    const float* W1  = (const float*)d_in[4];
    const float* b1  = (const float*)d_in[5];
    const float* W2  = (const float*)d_in[6];
    const float* b2  = (const float*)d_in[7];
    float* outp = (float*)d_out;               // pred[100000] ++ loss[1]

    char* wsb = (char*)d_ws;
    float*  dis   = (float*)wsb + OFF_DIS;
    int*    gcur  = (int*)wsb + OFF_GCUR;
    int*    bbase = (int*)wsb + OFF_BBASE;
    float*  part  = (float*)wsb + OFF_PARTL;
    __half* w1t   = (__half*)((int*)wsb + OFF_W1T);
    unsigned short* noff = (unsigned short*)((int*)wsb + OFF_NOFF);
    int*    cw    = (int*)wsb + OFF_CW;
    __half* bufA  = (__half*)((int*)wsb + OFF_A);     // emb16 -> x2'
    __half* bufB  = (__half*)((int*)wsb + OFF_B);     // x1' -> outf
    __half* oacc  = (__half*)((int*)wsb + OFF_OACC);
    __half* P     = (__half*)((int*)wsb + OFF_P);
    int*    tmp   = (int*)wsb + OFF_P;                // alias: dead before k_part

    const int T = 256;
    const int RGRID = (NNODES * DIM / 8 + T - 1) / T;   // 3125
    hipLaunchKernelGGL(k_cvt, dim3(6251), dim3(T), 0, stream, emb, bufA, W1, w1t, gcur);
    hipLaunchKernelGGL(k_fill1, dim3(NBLKF), dim3(1024), 0, stream, ei, gcur, tmp);
    hipLaunchKernelGGL(k_bscan, dim3(1), dim3(1024), 0, stream, gcur, bbase);
    hipLaunchKernelGGL(k_fill2, dim3(NB), dim3(T), 0, stream, gcur, bbase, tmp, dis, noff, cw);

    // layer 1: S = P(emb16, weighted inline); bufB = x1' = dis^2*S; oacc = a(emb + dis*S)
    hipLaunchKernelGGL((k_part<0>), dim3(2 * NBIN), dim3(T), 0, stream, bbase, noff, cw, dis, bufA, bufB, P);
    hipLaunchKernelGGL((k_reduce<0>), dim3(RGRID), dim3(T), 0, stream, dis, bufB, P, bufA, oacc, (__half*)nullptr);
    // layer 2: S = P(x1'); bufA = x2' = dis^2*S; oacc += a*dis*S
    hipLaunchKernelGGL((k_part<1>), dim3(2 * NBIN), dim3(T), 0, stream, bbase, noff, cw, dis, bufB, bufA, P);
    hipLaunchKernelGGL((k_reduce<1>), dim3(RGRID), dim3(T), 0, stream, dis, bufA, P, (const __half*)nullptr, oacc, (__half*)nullptr);
    // layer 3: S = P(x2'); outf(B) = oacc + a*dis*S
    hipLaunchKernelGGL((k_part<1>), dim3(2 * NBIN), dim3(T), 0, stream, bbase, noff, cw, dis, bufA, bufB, P);
    hipLaunchKernelGGL((k_reduce<2>), dim3(RGRID), dim3(T), 0, stream, dis, bufB, P, (const __half*)nullptr, oacc, bufB);

    const int MLPB = (NLABEL + 63) / 64;   // 1563
    hipLaunchKernelGGL(k_mlp, dim3(MLPB), dim3(T), 0, stream, bufB, eli, lbl, w1t, b1, W2, b2, outp, part);
    hipLaunchKernelGGL(k_loss, dim3(1), dim3(512), 0, stream, part, outp + NLABEL, MLPB);
}

// Round 15
// 200.103 us; speedup vs baseline: 8.7956x; 1.2210x over previous
//
#include <hip/hip_runtime.h>
#include <hip/hip_fp16.h>
#include <math.h>

// ---- problem constants (match reference) ----
#define NNODES 100000
#define NEDGES 1600000
#define NLABEL 100000
#define DIM    64
#define ALPHA  0.25f            // 1/(NUM_LAYERS+1)
#define NB     782               // coarse buckets of 128 nodes (dst >> 7)
#define NBLKF  256               // blocks for fill1 (1024 threads each)
#define BCAP   4096              // per-bucket tmp capacity (mean 2046, sigma 45)
#define XS_LD  136               // padded LDS row stride (halfs) for MFMA tiles

typedef _Float16 half8 __attribute__((ext_vector_type(8)));
typedef float    f32x4 __attribute__((ext_vector_type(4)));

// ---- workspace layout (u32 words) ----
constexpr size_t OFF_DIS    = 0;         // f32 [100096]
constexpr size_t OFF_ROWPTR = 100096;    // int [100001] (pad to 200192)
constexpr size_t OFF_BBASE  = 200192;    // int [NB+1]
constexpr size_t OFF_GCUR   = 201088;    // int [NB]
constexpr size_t OFF_CW     = 202880;    // int [1600000] (src only)
constexpr size_t OFF_EMB16  = 3402880;   // half[6400000] = 3200000 words
constexpr size_t OFF_X1     = 6602880;   // half[6400000] (aliased by tmp during fill)
constexpr size_t OFF_X2     = 9802880;   // half[6400000]
constexpr size_t OFF_OUTF16 = 13002880;  // half[6400000]
constexpr size_t OFF_PART   = 16202880;  // f32 [2048]
constexpr size_t OFF_W1T    = 16204928;  // half[8192] = 4096 words (W1 transposed)

// convert fp32 embedding -> fp16; extra block (bid==6250): zero gcur + build W1T
__global__ void k_cvt(const float* __restrict__ emb, __half* __restrict__ emb16,
                      const float* __restrict__ W1, __half* __restrict__ w1t,
                      int* __restrict__ gcur) {
    int bid = blockIdx.x;
    int tid = threadIdx.x;
    if (bid < 6250) {
        int i = bid * 256 + tid;             // one float4 / thread, exactly 1.6M
        float4 v = ((const float4*)emb)[i];
        float2 bits;
        ((__half2*)&bits)[0] = __float22half2_rn(make_float2(v.x, v.y));
        ((__half2*)&bits)[1] = __float22half2_rn(make_float2(v.z, v.w));
        ((float2*)emb16)[i] = bits;
    } else {
        for (int i = tid; i < NB; i += 256) gcur[i] = 0;
        for (int idx = tid; idx < 8192; idx += 256) {
            int j = idx & 63;                // hidden col
            int k = idx >> 6;                // k index
            w1t[j * 128 + k] = __float2half_rn(W1[k * 64 + j]);
        }
    }
}

// single-pass binning: per-block LDS hist -> one global reserve per bucket ->
// packed 4B records (src<<7 | dst&127) into fixed-capacity bucket regions.
__global__ __launch_bounds__(1024) void k_fill1(
    const int* __restrict__ ei, int* __restrict__ gcur,
    int* __restrict__ tmp) {
    __shared__ int hist[NB];
    __shared__ int base[NB];
    int tid = threadIdx.x;
    const int chunk = (((NEDGES + NBLKF - 1) / NBLKF) + 3) & ~3;   // 6252 (x4)
    int e0 = blockIdx.x * chunk;
    int e1 = min(e0 + chunk, NEDGES);
    for (int i = tid; i < NB; i += 1024) hist[i] = 0;
    __syncthreads();
    const int* srcs = ei;
    const int* dsts = ei + NEDGES;
    for (int e = e0 + tid * 4; e + 3 < e1; e += 4096) {
        int4 d = *(const int4*)(dsts + e);
        atomicAdd(&hist[d.x >> 7], 1);
        atomicAdd(&hist[d.y >> 7], 1);
        atomicAdd(&hist[d.z >> 7], 1);
        atomicAdd(&hist[d.w >> 7], 1);
    }
    __syncthreads();
    for (int b = tid; b < NB; b += 1024) {
        int c = hist[b];
        base[b] = c ? atomicAdd(&gcur[b], c) : 0;
        hist[b] = 0;
    }
    __syncthreads();
    for (int e = e0 + tid * 4; e + 3 < e1; e += 4096) {
        int4 s = *(const int4*)(srcs + e);
        int4 d = *(const int4*)(dsts + e);
        int b0 = d.x >> 7, b1 = d.y >> 7, b2 = d.z >> 7, b3 = d.w >> 7;
        int l0 = atomicAdd(&hist[b0], 1);
        int l1 = atomicAdd(&hist[b1], 1);
        int l2 = atomicAdd(&hist[b2], 1);
        int l3 = atomicAdd(&hist[b3], 1);
        int p0 = b0 * BCAP + min(base[b0] + l0, BCAP - 1);
        int p1 = b1 * BCAP + min(base[b1] + l1, BCAP - 1);
        int p2 = b2 * BCAP + min(base[b2] + l2, BCAP - 1);
        int p3 = b3 * BCAP + min(base[b3] + l3, BCAP - 1);
        tmp[p0] = (s.x << 7) | (d.x & 127);
        tmp[p1] = (s.y << 7) | (d.y & 127);
        tmp[p2] = (s.z << 7) | (d.z & 127);
        tmp[p3] = (s.w << 7) | (d.w & 127);
    }
}

// exclusive scan of bucket counts (in gcur) -> bucket bases
__global__ __launch_bounds__(1024) void k_bscan(
    const int* __restrict__ gcur, int* __restrict__ bbase) {
    __shared__ int s[1024];
    int tid = threadIdx.x;
    int v = (tid < NB) ? gcur[tid] : 0;
    s[tid] = v;
    __syncthreads();
    for (int off = 1; off < 1024; off <<= 1) {
        int t = s[tid];
        if (tid >= off) t += s[tid - off];
        __syncthreads();
        s[tid] = t;
        __syncthreads();
    }
    if (tid < NB) bbase[tid] = s[tid] - v;
    if (tid == NB) bbase[NB] = NEDGES;
}

// merged fill pass 2: per bucket — read tmp once into LDS, per-node degree,
// dis + rowptr, CSR reorder in LDS, coalesced stream-out of src records.
__global__ __launch_bounds__(256) void k_fill2(
    const int* __restrict__ bbase, const int* __restrict__ gcur,
    const int* __restrict__ tmp, float* __restrict__ dis,
    int* __restrict__ rowptr, int* __restrict__ cw) {
    __shared__ int raw[BCAP];
    __shared__ int seg[BCAP];
    __shared__ int dcnt[128];
    __shared__ int sc[128];
    __shared__ int cur[128];
    int b = blockIdx.x;
    int tid = threadIdx.x;
    int n0 = b << 7;
    int s0 = bbase[b];
    int n = gcur[b];
    const int* tb = tmp + (size_t)b * BCAP;
    if (tid < 128) dcnt[tid] = 0;
    __syncthreads();
    for (int i = tid; i < n; i += 256) {
        int t = tb[i];
        raw[i] = t;
        atomicAdd(&dcnt[t & 127], 1);
    }
    __syncthreads();
    int node = n0 + tid;
    if (tid < 128) {
        int d = dcnt[tid];
        if (node < NNODES) dis[node] = d ? rsqrtf((float)d) : 0.0f;
        sc[tid] = d;
    }
    __syncthreads();
    for (int off = 1; off < 128; off <<= 1) {
        int t = 0;
        if (tid < 128) {
            t = sc[tid];
            if (tid >= off) t += sc[tid - off];
        }
        __syncthreads();
        if (tid < 128) sc[tid] = t;
        __syncthreads();
    }
    if (tid < 128) {
        int excl = sc[tid] - dcnt[tid];
        if (node < NNODES) rowptr[node] = s0 + excl;
        cur[tid] = excl;
    }
    if (b == 0 && tid == 0) rowptr[NNODES] = NEDGES;
    __syncthreads();
    for (int i = tid; i < n; i += 256) {
        int t = raw[i];
        int p = atomicAdd(&cur[t & 127], 1);
        if (p < BCAP) seg[p] = t >> 7;   // src
    }
    __syncthreads();
    for (int i = tid; i < n; i += 256) cw[s0 + i] = seg[i];
}

// one wave per node; 4 edge-groups x 16 lanes; each lane owns 4 dims (8 B fp16).
// MODE 0/1: dst = x_next. MODE 2: fused out = ALPHA*(emb+x1+x2+y).
template <int MODE>
__global__ __launch_bounds__(256) void k_prop(
    const int* __restrict__ rowptr, const int* __restrict__ cw,
    const float* __restrict__ dis, const __half* __restrict__ xin,
    __half* __restrict__ dst, const __half* __restrict__ emb16,
    const __half* __restrict__ x1, const __half* __restrict__ x2) {
    int gt = blockIdx.x * 256 + threadIdx.x;
    int node = gt >> 6;
    if (node >= NNODES) return;
    int lane = threadIdx.x & 63;
    int g = lane >> 4;     // edge group 0..3
    int c = lane & 15;     // 4-dim chunk within row
    int r0 = __builtin_amdgcn_readfirstlane(rowptr[node]);
    int r1 = __builtin_amdgcn_readfirstlane(rowptr[node + 1]);
    float4 acc0 = {0.f, 0.f, 0.f, 0.f}, acc1 = {0.f, 0.f, 0.f, 0.f};
    float4 acc2 = {0.f, 0.f, 0.f, 0.f}, acc3 = {0.f, 0.f, 0.f, 0.f};
    int j = r0 + g;
    for (; j + 12 < r1; j += 16) {         // 4 edges per group in flight
        int s0 = cw[j], s1 = cw[j + 4], s2 = cw[j + 8], s3 = cw[j + 12];
        float w0 = dis[s0], w1 = dis[s1], w2 = dis[s2], w3 = dis[s3];
        float2 r0v = *(const float2*)(xin + (size_t)s0 * DIM + c * 4);
        float2 r1v = *(const float2*)(xin + (size_t)s1 * DIM + c * 4);
        float2 r2v = *(const float2*)(xin + (size_t)s2 * DIM + c * 4);
        float2 r3v = *(const float2*)(xin + (size_t)s3 * DIM + c * 4);
        float2 f0a = __half22float2(((__half2*)&r0v)[0]);
        float2 f0b = __half22float2(((__half2*)&r0v)[1]);
        float2 f1a = __half22float2(((__half2*)&r1v)[0]);
        float2 f1b = __half22float2(((__half2*)&r1v)[1]);
        float2 f2a = __half22float2(((__half2*)&r2v)[0]);
        float2 f2b = __half22float2(((__half2*)&r2v)[1]);
        float2 f3a = __half22float2(((__half2*)&r3v)[0]);
        float2 f3b = __half22float2(((__half2*)&r3v)[1]);
        acc0.x += w0 * f0a.x; acc0.y += w0 * f0a.y;
        acc0.z += w0 * f0b.x; acc0.w += w0 * f0b.y;
        acc1.x += w1 * f1a.x; acc1.y += w1 * f1a.y;
        acc1.z += w1 * f1b.x; acc1.w += w1 * f1b.y;
        acc2.x += w2 * f2a.x; acc2.y += w2 * f2a.y;
        acc2.z += w2 * f2b.x; acc2.w += w2 * f2b.y;
        acc3.x += w3 * f3a.x; acc3.y += w3 * f3a.y;
        acc3.z += w3 * f3b.x; acc3.w += w3 * f3b.y;
    }
    for (; j + 4 < r1; j += 8) {           // 2 edges
        int s0 = cw[j], s1 = cw[j + 4];
        float w0 = dis[s0], w1 = dis[s1];
        float2 r0v = *(const float2*)(xin + (size_t)s0 * DIM + c * 4);
        float2 r1v = *(const float2*)(xin + (size_t)s1 * DIM + c * 4);
        float2 f0a = __half22float2(((__half2*)&r0v)[0]);
        float2 f0b = __half22float2(((__half2*)&r0v)[1]);
        float2 f1a = __half22float2(((__half2*)&r1v)[0]);
        float2 f1b = __half22float2(((__half2*)&r1v)[1]);
        acc0.x += w0 * f0a.x; acc0.y += w0 * f0a.y;
        acc0.z += w0 * f0b.x; acc0.w += w0 * f0b.y;
        acc1.x += w1 * f1a.x; acc1.y += w1 * f1a.y;
        acc1.z += w1 * f1b.x; acc1.w += w1 * f1b.y;
    }
    for (; j < r1; j += 4) {               // 1 edge
        int s = cw[j];
        float w = dis[s];
        float2 rv = *(const float2*)(xin + (size_t)s * DIM + c * 4);
        float2 f0 = __half22float2(((__half2*)&rv)[0]);
        float2 f1 = __half22float2(((__half2*)&rv)[1]);
        acc0.x += w * f0.x; acc0.y += w * f0.y;
        acc0.z += w * f1.x; acc0.w += w * f1.y;
    }
    acc0.x += acc1.x; acc0.y += acc1.y; acc0.z += acc1.z; acc0.w += acc1.w;
    acc2.x += acc3.x; acc2.y += acc3.y; acc2.z += acc3.z; acc2.w += acc3.w;
    acc0.x += acc2.x; acc0.y += acc2.y; acc0.z += acc2.z; acc0.w += acc2.w;
    acc0.x += __shfl_xor(acc0.x, 16); acc0.y += __shfl_xor(acc0.y, 16);
    acc0.z += __shfl_xor(acc0.z, 16); acc0.w += __shfl_xor(acc0.w, 16);
    acc0.x += __shfl_xor(acc0.x, 32); acc0.y += __shfl_xor(acc0.y, 32);
    acc0.z += __shfl_xor(acc0.z, 32); acc0.w += __shfl_xor(acc0.w, 32);
    if (lane < 16) {
        float dn = dis[node];
        float yx = dn * acc0.x, yy = dn * acc0.y;
        float yz = dn * acc0.z, yw = dn * acc0.w;
        size_t idx = (size_t)node * DIM + c * 4;
        if (MODE == 2) {
            float2 eb = *(const float2*)(emb16 + idx);
            float2 ab = *(const float2*)(x1 + idx);
            float2 bb = *(const float2*)(x2 + idx);
            float2 e0 = __half22float2(((__half2*)&eb)[0]);
            float2 e1 = __half22float2(((__half2*)&eb)[1]);
            float2 a0 = __half22float2(((__half2*)&ab)[0]);
            float2 a1 = __half22float2(((__half2*)&ab)[1]);
            float2 b0 = __half22float2(((__half2*)&bb)[0]);
            float2 b1 = __half22float2(((__half2*)&bb)[1]);
            yx = ALPHA * (e0.x + a0.x + b0.x + yx);
            yy = ALPHA * (e0.y + a0.y + b0.y + yy);
            yz = ALPHA * (e1.x + a1.x + b1.x + yz);
            yw = ALPHA * (e1.y + a1.y + b1.y + yw);
        }
        float2 bits;
        ((__half2*)&bits)[0] = __float22half2_rn(make_float2(yx, yy));
        ((__half2*)&bits)[1] = __float22half2_rn(make_float2(yz, yw));
        *(float2*)(dst + idx) = bits;
    }
}

// MFMA MLP: 64 labels/block, 4 waves = 4 M-tiles of 16 labels.
// X[64][128] fp16 and W1T[64][128] fp16 staged in LDS (stride 136 halfs).
// D = X @ W1 via mfma_f32_16x16x32_f16; epilogue relu+W2 dot in registers.
__global__ __launch_bounds__(256) void k_mlp(
    const __half* __restrict__ outf, const int* __restrict__ eli,
    const float* __restrict__ lbl, const __half* __restrict__ w1t,
    const float* __restrict__ b1, const float* __restrict__ W2,
    const float* __restrict__ b2, float* __restrict__ pred,
    float* __restrict__ partial) {
    __shared__ _Float16 xs[64 * XS_LD];
    __shared__ _Float16 ws1[64 * XS_LD];
    __shared__ float wsum[4];
    int tid = threadIdx.x;
    int lb = blockIdx.x * 64;

    // stage W1T (64 rows x 16 chunks of 8 halfs)
    for (int idx = tid; idx < 1024; idx += 256) {
        int row = idx >> 4, ch = idx & 15;
        *(float4*)&ws1[row * XS_LD + ch * 8] = ((const float4*)w1t)[idx];
    }
    // gather 64 labels' concat rows into xs (fp16, [label][k])
    {
        int lab = tid >> 2, q = tid & 3;
        int l = lb + lab;
        int li = (l < NLABEL) ? l : (NLABEL - 1);
        int s = eli[li];
        int t = eli[NLABEL + li];
        const __half* srow = outf + (size_t)s * DIM;
        const __half* trow = outf + (size_t)t * DIM;
#pragma unroll
        for (int i = 0; i < 4; ++i) {
            int cc = q + 4 * i;           // chunk 0..15 (8 halfs each)
            const __half* row = (cc < 8) ? srow + cc * 8 : trow + (cc - 8) * 8;
            *(float4*)&xs[lab * XS_LD + cc * 8] = *(const float4*)row;
        }
    }
    __syncthreads();

    int wid = tid >> 6;          // M-tile
    int lane = tid & 63;
    int lrow = lane & 15;        // A row / B col / D col
    int kgrp = lane >> 4;        // k-group
    f32x4 acc[4];
#pragma unroll
    for (int nt = 0; nt < 4; ++nt) acc[nt] = (f32x4){0.f, 0.f, 0.f, 0.f};

#pragma unroll
    for (int ks = 0; ks < 4; ++ks) {
        half8 a = *(const half8*)&xs[(wid * 16 + lrow) * XS_LD + ks * 32 + kgrp * 8];
#pragma unroll
        for (int nt = 0; nt < 4; ++nt) {
            half8 b = *(const half8*)&ws1[(nt * 16 + lrow) * XS_LD + ks * 32 + kgrp * 8];
            acc[nt] = __builtin_amdgcn_mfma_f32_16x16x32_f16(a, b, acc[nt], 0, 0, 0);
        }
    }

    // epilogue: h = relu(acc + b1), p = h . W2 ; D col = lane&15, row = kgrp*4+reg
    float p[4] = {0.f, 0.f, 0.f, 0.f};
#pragma unroll
    for (int nt = 0; nt < 4; ++nt) {
        float b1v = b1[nt * 16 + lrow];
        float w2v = W2[nt * 16 + lrow];
#pragma unroll
        for (int r = 0; r < 4; ++r)
            p[r] += fmaxf(acc[nt][r] + b1v, 0.f) * w2v;
    }
#pragma unroll
    for (int off = 1; off <= 8; off <<= 1) {
#pragma unroll
        for (int r = 0; r < 4; ++r) p[r] += __shfl_xor(p[r], off);
    }
    float lsum = 0.f;
    if (lrow == 0) {
        float b2v = b2[0];
#pragma unroll
        for (int r = 0; r < 4; ++r) {
            int l = lb + wid * 16 + kgrp * 4 + r;
            if (l < NLABEL) {
                float predv = p[r] + b2v;
                pred[l] = predv;
                float d = predv - lbl[l];
                lsum += d * d;
            }
        }
    }
    lsum += __shfl_xor(lsum, 16);
    lsum += __shfl_xor(lsum, 32);
    if (lane == 0) wsum[wid] = lsum;
    __syncthreads();
    if (tid == 0) partial[blockIdx.x] = (wsum[0] + wsum[1]) + (wsum[2] + wsum[3]);
}

__global__ void k_loss(const float* __restrict__ partial, float* __restrict__ lossout,
                       int n) {
    __shared__ float s[512];
    int tid = threadIdx.x;
    float v = 0.f;
    for (int i = tid; i < n; i += 512) v += partial[i];
    s[tid] = v;
    __syncthreads();
    for (int off = 256; off >= 1; off >>= 1) {
        if (tid < off) s[tid] += s[tid + off];
        __syncthreads();
    }
    if (tid == 0) lossout[0] = s[0] / (float)NLABEL;
}

extern "C" void kernel_launch(void* const* d_in, const int* in_sizes, int n_in,
                              void* d_out, int out_size, void* d_ws, size_t ws_size,
                              hipStream_t stream) {
    const int*   ei  = (const int*)d_in[0];
    const int*   eli = (const int*)d_in[1];
    const float* lbl = (const float*)d_in[2];
    const float* emb = (const float*)d_in[3];
    const float* W1  = (const float*)d_in[4];
    const float* b1  = (const float*)d_in[5];
    const float* W2  = (const float*)d_in[6];
    const float* b2  = (const float*)d_in[7];
    float* outp = (float*)d_out;               // pred[100000] ++ loss[1]

    char* wsb = (char*)d_ws;
    float*  dis    = (float*)wsb + OFF_DIS;
    int*    rowptr = (int*)wsb + OFF_ROWPTR;
    int*    bbase  = (int*)wsb + OFF_BBASE;
    int*    gcur   = (int*)wsb + OFF_GCUR;
    int*    cw     = (int*)wsb + OFF_CW;
    __half* emb16  = (__half*)((int*)wsb + OFF_EMB16);
    __half* x1     = (__half*)((int*)wsb + OFF_X1);
    __half* x2     = (__half*)((int*)wsb + OFF_X2);
    __half* outf   = (__half*)((int*)wsb + OFF_OUTF16);
    float*  part   = (float*)wsb + OFF_PART;
    __half* w1t    = (__half*)((int*)wsb + OFF_W1T);
    int*    tmp    = (int*)wsb + OFF_X1;       // alias: dead before k_prop<0>

    const int T = 256;
    hipLaunchKernelGGL(k_cvt, dim3(6251), dim3(T), 0, stream, emb, emb16, W1, w1t, gcur);
    hipLaunchKernelGGL(k_fill1, dim3(NBLKF), dim3(1024), 0, stream, ei, gcur, tmp);
    hipLaunchKernelGGL(k_bscan, dim3(1), dim3(1024), 0, stream, gcur, bbase);
    hipLaunchKernelGGL(k_fill2, dim3(NB), dim3(T), 0, stream, bbase, gcur, tmp, dis, rowptr, cw);

    // x1 = P(emb); x2 = P(x1); outf = ALPHA*(emb + x1 + x2 + P(x2))   [all fp16]
    dim3 pgrid((NNODES * 64) / T);
    hipLaunchKernelGGL((k_prop<0>), pgrid, dim3(T), 0, stream, rowptr, cw, dis, emb16, x1,   nullptr, nullptr, nullptr);
    hipLaunchKernelGGL((k_prop<1>), pgrid, dim3(T), 0, stream, rowptr, cw, dis, x1,    x2,   nullptr, nullptr, nullptr);
    hipLaunchKernelGGL((k_prop<2>), pgrid, dim3(T), 0, stream, rowptr, cw, dis, x2,    outf, emb16, x1, x2);

    const int MLPB = (NLABEL + 63) / 64;   // 1563
    hipLaunchKernelGGL(k_mlp, dim3(MLPB), dim3(T), 0, stream, outf, eli, lbl, w1t, b1, W2, b2, outp, part);
    hipLaunchKernelGGL(k_loss, dim3(1), dim3(512), 0, stream, part, outp + NLABEL, MLPB);
}